// Round 1
// baseline (411.664 us; speedup 1.0000x reference)
//
#include <hip/hip_runtime.h>

#define N_NODES 50000
#define N_EDGES 800000

// ---------------------------------------------------------------------------
// Edge-index dtype detection: jax may hand us int32 (x64 disabled) or int64.
// Reading int32 pairs as int64 gives values >= 2^32 w.h.p., so checking the
// first 256 int64-interpreted values against [0, N_NODES) is decisive.
// ---------------------------------------------------------------------------
__device__ __forceinline__ int load_idx(const void* ei, int is64, long long pos) {
  return is64 ? (int)((const long long*)ei)[pos] : ((const int*)ei)[pos];
}

__global__ void detect_kernel(const void* __restrict__ ei, int* __restrict__ flag) {
  if (threadIdx.x == 0 && blockIdx.x == 0) {
    const long long* e64 = (const long long*)ei;
    int ok = 1;
    for (int i = 0; i < 256; ++i) {
      long long v = e64[i];
      if (v < 0 || v >= N_NODES) { ok = 0; break; }
    }
    *flag = ok;
  }
}

// ---------------------------------------------------------------------------
// CSR build: histogram by dst -> exclusive scan -> slot scatter (src list)
// ---------------------------------------------------------------------------
__global__ __launch_bounds__(256) void hist_kernel(const void* __restrict__ ei,
                                                   const int* __restrict__ flag,
                                                   int* __restrict__ cnt) {
  int e = blockIdx.x * 256 + threadIdx.x;
  if (e >= N_EDGES) return;
  int dst = load_idx(ei, *flag, (long long)N_EDGES + e);
  atomicAdd(&cnt[dst], 1);
}

__global__ __launch_bounds__(1024) void scan_kernel(const int* __restrict__ cnt,
                                                    int* __restrict__ rowptr,
                                                    int* __restrict__ cursor) {
  __shared__ int partial[1024];
  int tid = threadIdx.x;
  const int CHUNK = 49;  // 1024*49 = 50176 >= 50000
  int lo = tid * CHUNK;
  int hi = lo + CHUNK; if (hi > N_NODES) hi = N_NODES;
  int s = 0;
  for (int i = lo; i < hi; ++i) s += cnt[i];
  partial[tid] = s;
  __syncthreads();
  for (int off = 1; off < 1024; off <<= 1) {
    int v = (tid >= off) ? partial[tid - off] : 0;
    __syncthreads();
    partial[tid] += v;
    __syncthreads();
  }
  int base = (tid == 0) ? 0 : partial[tid - 1];
  for (int i = lo; i < hi; ++i) {
    rowptr[i] = base; cursor[i] = base;
    base += cnt[i];
  }
  if (tid == 0) rowptr[N_NODES] = partial[1023];
}

__global__ __launch_bounds__(256) void scatter_kernel(const void* __restrict__ ei,
                                                      const int* __restrict__ flag,
                                                      int* __restrict__ cursor,
                                                      int* __restrict__ col) {
  int e = blockIdx.x * 256 + threadIdx.x;
  if (e >= N_EDGES) return;
  int f = *flag;
  int src = load_idx(ei, f, e);
  int dst = load_idx(ei, f, (long long)N_EDGES + e);
  int slot = atomicAdd(&cursor[dst], 1);
  col[slot] = src;
}

// ---------------------------------------------------------------------------
// Gather-sum: one wave per node, float2 per lane (128 dims / 64 lanes).
// outp[n] = xin[n] + sum_{s in col[rowptr[n]..rowptr[n+1])} xin[s]
// ---------------------------------------------------------------------------
__global__ __launch_bounds__(256) void gather_kernel(const float* __restrict__ xin,
                                                     const int* __restrict__ rowptr,
                                                     const int* __restrict__ col,
                                                     float* __restrict__ outp) {
  int gw = (blockIdx.x * 256 + threadIdx.x) >> 6;
  int lane = threadIdx.x & 63;
  if (gw >= N_NODES) return;
  const float2* x2 = (const float2*)xin;
  float2 acc = x2[(size_t)gw * 64 + lane];
  int i = rowptr[gw], end = rowptr[gw + 1];
  for (; i + 1 < end; i += 2) {
    int s0 = col[i], s1 = col[i + 1];
    float2 v0 = x2[(size_t)s0 * 64 + lane];
    float2 v1 = x2[(size_t)s1 * 64 + lane];
    acc.x += v0.x + v1.x;
    acc.y += v0.y + v1.y;
  }
  if (i < end) {
    int s0 = col[i];
    float2 v0 = x2[(size_t)s0 * 64 + lane];
    acc.x += v0.x; acc.y += v0.y;
  }
  ((float2*)outp)[(size_t)gw * 64 + lane] = acc;
}

// ---------------------------------------------------------------------------
// Transpose weights once into ws: Wt1[k*128+o] = W1[o*128+k]; Wt2[k*40+c].
// Makes GEMM weight reads lane-consecutive float4 from L1/L2.
// ---------------------------------------------------------------------------
__global__ __launch_bounds__(256) void transpose_w_kernel(const float* __restrict__ W1,
                                                          const float* __restrict__ W2,
                                                          float* __restrict__ Wt1,
                                                          float* __restrict__ Wt2) {
  int i = blockIdx.x * 256 + threadIdx.x;
  if (i < 128 * 128) {
    int o = i >> 7, k = i & 127;
    Wt1[k * 128 + o] = W1[i];
  }
  int j = i - 128 * 128;
  if (j >= 0 && j < 40 * 128) {
    int c = j >> 7, k = j & 127;
    Wt2[k * 40 + c] = W2[j];
  }
}

#define FMA4(acc, h, w0, w1, w2, w3)                                               \
  acc.x = fmaf(h.x, w0.x, acc.x); acc.x = fmaf(h.y, w1.x, acc.x);                  \
  acc.x = fmaf(h.z, w2.x, acc.x); acc.x = fmaf(h.w, w3.x, acc.x);                  \
  acc.y = fmaf(h.x, w0.y, acc.y); acc.y = fmaf(h.y, w1.y, acc.y);                  \
  acc.y = fmaf(h.z, w2.y, acc.y); acc.y = fmaf(h.w, w3.y, acc.y);                  \
  acc.z = fmaf(h.x, w0.z, acc.z); acc.z = fmaf(h.y, w1.z, acc.z);                  \
  acc.z = fmaf(h.z, w2.z, acc.z); acc.z = fmaf(h.w, w3.z, acc.z);                  \
  acc.w = fmaf(h.x, w0.w, acc.w); acc.w = fmaf(h.y, w1.w, acc.w);                  \
  acc.w = fmaf(h.z, w2.w, acc.w); acc.w = fmaf(h.w, w3.w, acc.w);

// ---------------------------------------------------------------------------
// GEMM1: h1[n][o] = relu(sum_k hpre[n][k] * W1[o][k]), 50000x128 @ 128x128.
// 64 rows/block staged in LDS; weights read from transposed global (L2-hot).
// Thread computes 8 rows x 4 cols.
// ---------------------------------------------------------------------------
__global__ __launch_bounds__(256) void gemm1_kernel(const float* __restrict__ hpre,
                                                    const float* __restrict__ Wt,
                                                    float* __restrict__ h1) {
  __shared__ float4 Hs[64 * 32];  // 64 rows x 128 floats = 32 KB
  int tid = threadIdx.x;
  int n0 = blockIdx.x * 64;
  const float4* hp4 = (const float4*)hpre;
  #pragma unroll
  for (int it = 0; it < 8; ++it) {
    int i = tid + it * 256;
    int r = i >> 5, k4 = i & 31;
    int n = n0 + r;
    float4 v = make_float4(0.f, 0.f, 0.f, 0.f);
    if (n < N_NODES) v = hp4[(size_t)n * 32 + k4];
    Hs[i] = v;
  }
  __syncthreads();
  int o4 = tid & 31;          // cols 4*o4 .. 4*o4+3
  int r0 = (tid >> 5) * 8;    // 8 rows
  float4 acc[8];
  #pragma unroll
  for (int j = 0; j < 8; ++j) acc[j] = make_float4(0.f, 0.f, 0.f, 0.f);
  const float4* Wt4 = (const float4*)Wt;  // [k][o] layout, row = 32 float4
  #pragma unroll 4
  for (int k4 = 0; k4 < 32; ++k4) {
    float4 w0 = Wt4[(k4 * 4 + 0) * 32 + o4];
    float4 w1 = Wt4[(k4 * 4 + 1) * 32 + o4];
    float4 w2 = Wt4[(k4 * 4 + 2) * 32 + o4];
    float4 w3 = Wt4[(k4 * 4 + 3) * 32 + o4];
    #pragma unroll
    for (int j = 0; j < 8; ++j) {
      float4 h = Hs[(r0 + j) * 32 + k4];
      FMA4(acc[j], h, w0, w1, w2, w3);
    }
  }
  float4* out4 = (float4*)h1;
  #pragma unroll
  for (int j = 0; j < 8; ++j) {
    int n = n0 + r0 + j;
    if (n < N_NODES) {
      float4 v = acc[j];
      v.x = fmaxf(v.x, 0.f); v.y = fmaxf(v.y, 0.f);
      v.z = fmaxf(v.z, 0.f); v.w = fmaxf(v.w, 0.f);
      out4[(size_t)n * 32 + o4] = v;
    }
  }
}

// ---------------------------------------------------------------------------
// GEMM2: out[n][c] = sum_k hpre2[n][k] * W2[c][k], c < 40.
// 320 threads = 10 col-groups x 32 row-pairs; 64 rows/block.
// ---------------------------------------------------------------------------
__global__ __launch_bounds__(320) void gemm2_kernel(const float* __restrict__ hpre,
                                                    const float* __restrict__ Wt2,
                                                    float* __restrict__ outp) {
  __shared__ float4 Hs[64 * 33];  // stride 33 f4 to spread banks
  int tid = threadIdx.x;
  int n0 = blockIdx.x * 64;
  const float4* hp4 = (const float4*)hpre;
  for (int i = tid; i < 64 * 32; i += 320) {
    int r = i >> 5, k4 = i & 31;
    int n = n0 + r;
    float4 v = make_float4(0.f, 0.f, 0.f, 0.f);
    if (n < N_NODES) v = hp4[(size_t)n * 32 + k4];
    Hs[r * 33 + k4] = v;
  }
  __syncthreads();
  int cg = tid % 10;          // cols 4*cg .. 4*cg+3
  int r0 = (tid / 10) * 2;    // rows r0, r0+1
  float4 acc0 = make_float4(0.f, 0.f, 0.f, 0.f);
  float4 acc1 = make_float4(0.f, 0.f, 0.f, 0.f);
  const float4* Wt4 = (const float4*)Wt2;  // [k][c], row = 10 float4
  #pragma unroll 4
  for (int k4 = 0; k4 < 32; ++k4) {
    float4 w0 = Wt4[(k4 * 4 + 0) * 10 + cg];
    float4 w1 = Wt4[(k4 * 4 + 1) * 10 + cg];
    float4 w2 = Wt4[(k4 * 4 + 2) * 10 + cg];
    float4 w3 = Wt4[(k4 * 4 + 3) * 10 + cg];
    float4 h0 = Hs[(r0    ) * 33 + k4];
    float4 h1v = Hs[(r0 + 1) * 33 + k4];
    FMA4(acc0, h0, w0, w1, w2, w3);
    FMA4(acc1, h1v, w0, w1, w2, w3);
  }
  int n = n0 + r0;
  float4* o4p = (float4*)outp;
  if (n < N_NODES)     o4p[(size_t)n * 10 + cg] = acc0;
  if (n + 1 < N_NODES) o4p[(size_t)(n + 1) * 10 + cg] = acc1;
}

// ---------------------------------------------------------------------------
extern "C" void kernel_launch(void* const* d_in, const int* in_sizes, int n_in,
                              void* d_out, int out_size, void* d_ws, size_t ws_size,
                              hipStream_t stream) {
  const float* x  = (const float*)d_in[0];
  const void*  ei = d_in[1];
  const float* W1 = (const float*)d_in[2];
  const float* W2 = (const float*)d_in[3];
  float* out = (float*)d_out;

  // ws layout (4-byte units)
  int* cnt    = (int*)d_ws;                 // 50048
  int* rowptr = cnt + 50048;                // 50048
  int* cursor = rowptr + 50048;             // 50048
  int* col    = cursor + 50048;             // 800000
  int* flag   = col + N_EDGES;              // 1 (at 950144)
  float* hpre = (float*)d_ws + 950160;      // 6.4M floats, 16B aligned
  float* h1   = hpre + (size_t)N_NODES * 128;
  float* Wt1  = h1 + (size_t)N_NODES * 128; // 16384
  float* Wt2  = Wt1 + 128 * 128;            // 5120

  hipMemsetAsync(cnt, 0, (N_NODES + 1) * sizeof(int), stream);
  detect_kernel<<<1, 64, 0, stream>>>(ei, flag);
  transpose_w_kernel<<<(128 * 128 + 40 * 128 + 255) / 256, 256, 0, stream>>>(W1, W2, Wt1, Wt2);
  hist_kernel<<<(N_EDGES + 255) / 256, 256, 0, stream>>>(ei, flag, cnt);
  scan_kernel<<<1, 1024, 0, stream>>>(cnt, rowptr, cursor);
  scatter_kernel<<<(N_EDGES + 255) / 256, 256, 0, stream>>>(ei, flag, cursor, col);

  // Layer 1: hpre = x + A*x ; h1 = relu(hpre @ W1^T)
  gather_kernel<<<(N_NODES * 64) / 256, 256, 0, stream>>>(x, rowptr, col, hpre);
  gemm1_kernel<<<(N_NODES + 63) / 64, 256, 0, stream>>>(hpre, Wt1, h1);

  // Layer 2: hpre = h1 + A*h1 ; out = hpre @ W2^T
  gather_kernel<<<(N_NODES * 64) / 256, 256, 0, stream>>>(h1, rowptr, col, hpre);
  gemm2_kernel<<<(N_NODES + 63) / 64, 320, 0, stream>>>(hpre, Wt2, out);
}

// Round 2
// 302.334 us; speedup vs baseline: 1.3616x; 1.3616x over previous
//
#include <hip/hip_runtime.h>

#define N_NODES 50000
#define N_EDGES 800000
#define SCAN_BLK 1024                       // elements per scan block
#define SCAN_NB  ((N_NODES + SCAN_BLK - 1) / SCAN_BLK)   // 49
#define CNT_PAD  (SCAN_NB * SCAN_BLK)       // 50176, padded so int4 reads are safe

// ---------------------------------------------------------------------------
// Edge-index dtype detection (wave-parallel). jax may hand us int32 or int64.
// Reading int32 pairs as int64: high word is a random value in [0,50000),
// ~never 0, so range check on 64 consecutive int64 values is decisive.
// ---------------------------------------------------------------------------
__device__ __forceinline__ int load_idx(const void* ei, int is64, long long pos) {
  return is64 ? (int)((const long long*)ei)[pos] : ((const int*)ei)[pos];
}

__global__ void detect_kernel(const void* __restrict__ ei, int* __restrict__ flag) {
  const long long* e64 = (const long long*)ei;
  long long v = e64[threadIdx.x];
  int ok = (v >= 0 && v < N_NODES);
  unsigned long long m = __ballot(ok);
  if (threadIdx.x == 0) *flag = (m == ~0ull) ? 1 : 0;
}

// ---------------------------------------------------------------------------
// CSR build: histogram by dst -> 3-phase coalesced scan -> slot scatter
// ---------------------------------------------------------------------------
__global__ __launch_bounds__(256) void hist_kernel(const void* __restrict__ ei,
                                                   const int* __restrict__ flag,
                                                   int* __restrict__ cnt) {
  int e = blockIdx.x * 256 + threadIdx.x;
  if (e >= N_EDGES) return;
  int dst = load_idx(ei, *flag, (long long)N_EDGES + e);
  atomicAdd(&cnt[dst], 1);
}

// Phase A: per-block (1024 elems) sums. cnt padded to CNT_PAD with zeros.
__global__ __launch_bounds__(256) void scanA_kernel(const int* __restrict__ cnt,
                                                    int* __restrict__ bsum) {
  __shared__ int sdata[256];
  int tid = threadIdx.x;
  const int4* c4 = (const int4*)cnt;
  int4 v = c4[blockIdx.x * 256 + tid];
  sdata[tid] = v.x + v.y + v.z + v.w;
  __syncthreads();
  #pragma unroll
  for (int off = 128; off > 0; off >>= 1) {
    if (tid < off) sdata[tid] += sdata[tid + off];
    __syncthreads();
  }
  if (tid == 0) bsum[blockIdx.x] = sdata[0];
}

// Phase B: exclusive scan of the 49 block sums (tiny).
__global__ void scanB_kernel(const int* __restrict__ bsum,
                             int* __restrict__ boff,
                             int* __restrict__ rowptr) {
  __shared__ int s[SCAN_NB];
  int tid = threadIdx.x;
  if (tid < SCAN_NB) s[tid] = bsum[tid];
  __syncthreads();
  if (tid == 0) {
    int acc = 0;
    for (int i = 0; i < SCAN_NB; ++i) { int t = s[i]; s[i] = acc; acc += t; }
    rowptr[N_NODES] = acc;
  }
  __syncthreads();
  if (tid < SCAN_NB) boff[tid] = s[tid];
}

// Phase C: block-local exclusive scan + block offset -> rowptr & cursor.
__global__ __launch_bounds__(256) void scanC_kernel(const int* __restrict__ cnt,
                                                    const int* __restrict__ boff,
                                                    int* __restrict__ rowptr,
                                                    int* __restrict__ cursor) {
  __shared__ int sdata[256];
  int tid = threadIdx.x;
  const int4* c4 = (const int4*)cnt;
  int4 v = c4[blockIdx.x * 256 + tid];
  int s = v.x + v.y + v.z + v.w;
  sdata[tid] = s;
  __syncthreads();
  #pragma unroll
  for (int off = 1; off < 256; off <<= 1) {
    int t = (tid >= off) ? sdata[tid - off] : 0;
    __syncthreads();
    sdata[tid] += t;
    __syncthreads();
  }
  int excl = ((tid == 0) ? 0 : sdata[tid - 1]) + boff[blockIdx.x];
  int p0 = excl, p1 = p0 + v.x, p2 = p1 + v.y, p3 = p2 + v.z;
  int idx = blockIdx.x * SCAN_BLK + tid * 4;
  int4 r = make_int4(p0, p1, p2, p3);
  if (idx + 3 < N_NODES) {
    ((int4*)rowptr)[idx >> 2] = r;
    ((int4*)cursor)[idx >> 2] = r;
  } else {
    int p[4] = {p0, p1, p2, p3};
    #pragma unroll
    for (int j = 0; j < 4; ++j)
      if (idx + j < N_NODES) { rowptr[idx + j] = p[j]; cursor[idx + j] = p[j]; }
  }
}

__global__ __launch_bounds__(256) void scatter_kernel(const void* __restrict__ ei,
                                                      const int* __restrict__ flag,
                                                      int* __restrict__ cursor,
                                                      int* __restrict__ col) {
  int e = blockIdx.x * 256 + threadIdx.x;
  if (e >= N_EDGES) return;
  int f = *flag;
  int src = load_idx(ei, f, e);
  int dst = load_idx(ei, f, (long long)N_EDGES + e);
  int slot = atomicAdd(&cursor[dst], 1);
  col[slot] = src;
}

// ---------------------------------------------------------------------------
// Gather-sum: one wave per node, float2 per lane (128 dims / 64 lanes).
// outp[n] = xin[n] + sum_{s in col[rowptr[n]..rowptr[n+1])} xin[s]
// ---------------------------------------------------------------------------
__global__ __launch_bounds__(256) void gather_kernel(const float* __restrict__ xin,
                                                     const int* __restrict__ rowptr,
                                                     const int* __restrict__ col,
                                                     float* __restrict__ outp) {
  int gw = (blockIdx.x * 256 + threadIdx.x) >> 6;
  int lane = threadIdx.x & 63;
  if (gw >= N_NODES) return;
  const float2* x2 = (const float2*)xin;
  float2 acc = x2[(size_t)gw * 64 + lane];
  int i = rowptr[gw], end = rowptr[gw + 1];
  for (; i + 3 < end; i += 4) {
    int s0 = col[i], s1 = col[i + 1], s2 = col[i + 2], s3 = col[i + 3];
    float2 v0 = x2[(size_t)s0 * 64 + lane];
    float2 v1 = x2[(size_t)s1 * 64 + lane];
    float2 v2 = x2[(size_t)s2 * 64 + lane];
    float2 v3 = x2[(size_t)s3 * 64 + lane];
    acc.x += (v0.x + v1.x) + (v2.x + v3.x);
    acc.y += (v0.y + v1.y) + (v2.y + v3.y);
  }
  for (; i < end; ++i) {
    int s0 = col[i];
    float2 v0 = x2[(size_t)s0 * 64 + lane];
    acc.x += v0.x; acc.y += v0.y;
  }
  ((float2*)outp)[(size_t)gw * 64 + lane] = acc;
}

// ---------------------------------------------------------------------------
// Transpose weights once into ws: Wt1[k*128+o] = W1[o*128+k]; Wt2[k*40+c].
// ---------------------------------------------------------------------------
__global__ __launch_bounds__(256) void transpose_w_kernel(const float* __restrict__ W1,
                                                          const float* __restrict__ W2,
                                                          float* __restrict__ Wt1,
                                                          float* __restrict__ Wt2) {
  int i = blockIdx.x * 256 + threadIdx.x;
  if (i < 128 * 128) {
    int o = i >> 7, k = i & 127;
    Wt1[k * 128 + o] = W1[i];
  }
  int j = i - 128 * 128;
  if (j >= 0 && j < 40 * 128) {
    int c = j >> 7, k = j & 127;
    Wt2[k * 40 + c] = W2[j];
  }
}

#define FMA4(acc, h, w0, w1, w2, w3)                                               \
  acc.x = fmaf(h.x, w0.x, acc.x); acc.x = fmaf(h.y, w1.x, acc.x);                  \
  acc.x = fmaf(h.z, w2.x, acc.x); acc.x = fmaf(h.w, w3.x, acc.x);                  \
  acc.y = fmaf(h.x, w0.y, acc.y); acc.y = fmaf(h.y, w1.y, acc.y);                  \
  acc.y = fmaf(h.z, w2.y, acc.y); acc.y = fmaf(h.w, w3.y, acc.y);                  \
  acc.z = fmaf(h.x, w0.z, acc.z); acc.z = fmaf(h.y, w1.z, acc.z);                  \
  acc.z = fmaf(h.z, w2.z, acc.z); acc.z = fmaf(h.w, w3.z, acc.z);                  \
  acc.w = fmaf(h.x, w0.w, acc.w); acc.w = fmaf(h.y, w1.w, acc.w);                  \
  acc.w = fmaf(h.z, w2.w, acc.w); acc.w = fmaf(h.w, w3.w, acc.w);

// ---------------------------------------------------------------------------
// GEMM1: h1[n][o] = relu(sum_k hpre[n][k] * W1[o][k]), 50000x128 @ 128x128.
// ---------------------------------------------------------------------------
__global__ __launch_bounds__(256) void gemm1_kernel(const float* __restrict__ hpre,
                                                    const float* __restrict__ Wt,
                                                    float* __restrict__ h1) {
  __shared__ float4 Hs[64 * 32];  // 64 rows x 128 floats = 32 KB
  int tid = threadIdx.x;
  int n0 = blockIdx.x * 64;
  const float4* hp4 = (const float4*)hpre;
  #pragma unroll
  for (int it = 0; it < 8; ++it) {
    int i = tid + it * 256;
    int r = i >> 5, k4 = i & 31;
    int n = n0 + r;
    float4 v = make_float4(0.f, 0.f, 0.f, 0.f);
    if (n < N_NODES) v = hp4[(size_t)n * 32 + k4];
    Hs[i] = v;
  }
  __syncthreads();
  int o4 = tid & 31;          // cols 4*o4 .. 4*o4+3
  int r0 = (tid >> 5) * 8;    // 8 rows
  float4 acc[8];
  #pragma unroll
  for (int j = 0; j < 8; ++j) acc[j] = make_float4(0.f, 0.f, 0.f, 0.f);
  const float4* Wt4 = (const float4*)Wt;  // [k][o] layout, row = 32 float4
  #pragma unroll 4
  for (int k4 = 0; k4 < 32; ++k4) {
    float4 w0 = Wt4[(k4 * 4 + 0) * 32 + o4];
    float4 w1 = Wt4[(k4 * 4 + 1) * 32 + o4];
    float4 w2 = Wt4[(k4 * 4 + 2) * 32 + o4];
    float4 w3 = Wt4[(k4 * 4 + 3) * 32 + o4];
    #pragma unroll
    for (int j = 0; j < 8; ++j) {
      float4 h = Hs[(r0 + j) * 32 + k4];
      FMA4(acc[j], h, w0, w1, w2, w3);
    }
  }
  float4* out4 = (float4*)h1;
  #pragma unroll
  for (int j = 0; j < 8; ++j) {
    int n = n0 + r0 + j;
    if (n < N_NODES) {
      float4 v = acc[j];
      v.x = fmaxf(v.x, 0.f); v.y = fmaxf(v.y, 0.f);
      v.z = fmaxf(v.z, 0.f); v.w = fmaxf(v.w, 0.f);
      out4[(size_t)n * 32 + o4] = v;
    }
  }
}

// ---------------------------------------------------------------------------
// GEMM2: out[n][c] = sum_k hpre2[n][k] * W2[c][k], c < 40.
// ---------------------------------------------------------------------------
__global__ __launch_bounds__(320) void gemm2_kernel(const float* __restrict__ hpre,
                                                    const float* __restrict__ Wt2,
                                                    float* __restrict__ outp) {
  __shared__ float4 Hs[64 * 33];  // stride 33 f4 to spread banks
  int tid = threadIdx.x;
  int n0 = blockIdx.x * 64;
  const float4* hp4 = (const float4*)hpre;
  for (int i = tid; i < 64 * 32; i += 320) {
    int r = i >> 5, k4 = i & 31;
    int n = n0 + r;
    float4 v = make_float4(0.f, 0.f, 0.f, 0.f);
    if (n < N_NODES) v = hp4[(size_t)n * 32 + k4];
    Hs[r * 33 + k4] = v;
  }
  __syncthreads();
  int cg = tid % 10;          // cols 4*cg .. 4*cg+3
  int r0 = (tid / 10) * 2;    // rows r0, r0+1
  float4 acc0 = make_float4(0.f, 0.f, 0.f, 0.f);
  float4 acc1 = make_float4(0.f, 0.f, 0.f, 0.f);
  const float4* Wt4 = (const float4*)Wt2;  // [k][c], row = 10 float4
  #pragma unroll 4
  for (int k4 = 0; k4 < 32; ++k4) {
    float4 w0 = Wt4[(k4 * 4 + 0) * 10 + cg];
    float4 w1 = Wt4[(k4 * 4 + 1) * 10 + cg];
    float4 w2 = Wt4[(k4 * 4 + 2) * 10 + cg];
    float4 w3 = Wt4[(k4 * 4 + 3) * 10 + cg];
    float4 h0 = Hs[(r0    ) * 33 + k4];
    float4 h1v = Hs[(r0 + 1) * 33 + k4];
    FMA4(acc0, h0, w0, w1, w2, w3);
    FMA4(acc1, h1v, w0, w1, w2, w3);
  }
  int n = n0 + r0;
  float4* o4p = (float4*)outp;
  if (n < N_NODES)     o4p[(size_t)n * 10 + cg] = acc0;
  if (n + 1 < N_NODES) o4p[(size_t)(n + 1) * 10 + cg] = acc1;
}

// ---------------------------------------------------------------------------
extern "C" void kernel_launch(void* const* d_in, const int* in_sizes, int n_in,
                              void* d_out, int out_size, void* d_ws, size_t ws_size,
                              hipStream_t stream) {
  const float* x  = (const float*)d_in[0];
  const void*  ei = d_in[1];
  const float* W1 = (const float*)d_in[2];
  const float* W2 = (const float*)d_in[3];
  float* out = (float*)d_out;

  // ws layout (4-byte units)
  int* cnt    = (int*)d_ws;                 // CNT_PAD = 50176 (zeroed)
  int* rowptr = cnt + CNT_PAD;              // 50176 (uses 50001)
  int* cursor = rowptr + CNT_PAD;           // 50176
  int* col    = cursor + CNT_PAD;           // 800000
  int* flag   = col + N_EDGES;              // 1  (+15 pad)
  int* bsum   = flag + 16;                  // 64
  int* boff   = bsum + 64;                  // 64
  float* hpre = (float*)(boff + 64);        // 6.4M floats (offset 950672, 16B aligned)
  float* h1   = hpre + (size_t)N_NODES * 128;
  float* Wt1  = h1 + (size_t)N_NODES * 128; // 16384
  float* Wt2  = Wt1 + 128 * 128;            // 5120

  hipMemsetAsync(cnt, 0, CNT_PAD * sizeof(int), stream);
  detect_kernel<<<1, 64, 0, stream>>>(ei, flag);
  transpose_w_kernel<<<(128 * 128 + 40 * 128 + 255) / 256, 256, 0, stream>>>(W1, W2, Wt1, Wt2);
  hist_kernel<<<(N_EDGES + 255) / 256, 256, 0, stream>>>(ei, flag, cnt);
  scanA_kernel<<<SCAN_NB, 256, 0, stream>>>(cnt, bsum);
  scanB_kernel<<<1, 64, 0, stream>>>(bsum, boff, rowptr);
  scanC_kernel<<<SCAN_NB, 256, 0, stream>>>(cnt, boff, rowptr, cursor);
  scatter_kernel<<<(N_EDGES + 255) / 256, 256, 0, stream>>>(ei, flag, cursor, col);

  // Layer 1: hpre = x + A*x ; h1 = relu(hpre @ W1^T)
  gather_kernel<<<(N_NODES * 64) / 256, 256, 0, stream>>>(x, rowptr, col, hpre);
  gemm1_kernel<<<(N_NODES + 63) / 64, 256, 0, stream>>>(hpre, Wt1, h1);

  // Layer 2: hpre = h1 + A*h1 ; out = hpre @ W2^T
  gather_kernel<<<(N_NODES * 64) / 256, 256, 0, stream>>>(h1, rowptr, col, hpre);
  gemm2_kernel<<<(N_NODES + 63) / 64, 320, 0, stream>>>(hpre, Wt2, out);
}

// Round 3
// 268.035 us; speedup vs baseline: 1.5359x; 1.1280x over previous
//
#include <hip/hip_runtime.h>

#define N_NODES 50000
#define N_EDGES 800000
#define SCAN_BLK 1024
#define SCAN_NB  ((N_NODES + SCAN_BLK - 1) / SCAN_BLK)   // 49
#define CNT_PAD  (SCAN_NB * SCAN_BLK)                    // 50176

__device__ __forceinline__ int load_idx(const void* ei, int is64, long long pos) {
  return is64 ? (int)((const long long*)ei)[pos] : ((const int*)ei)[pos];
}

// ---------------------------------------------------------------------------
// prep: block 0 = dtype detect; blocks 1..49 zero cnt (int4); blocks 50..133
// transpose W1->Wt1 [k][o] and W2->Wt2 [k][c].
// ---------------------------------------------------------------------------
__global__ __launch_bounds__(256) void prep_kernel(const void* __restrict__ ei,
                                                   const float* __restrict__ W1,
                                                   const float* __restrict__ W2,
                                                   int* __restrict__ flag,
                                                   int* __restrict__ cnt,
                                                   float* __restrict__ Wt1,
                                                   float* __restrict__ Wt2) {
  int b = blockIdx.x, tid = threadIdx.x;
  if (b == 0) {
    if (tid < 64) {
      const long long* e64 = (const long long*)ei;
      long long v = e64[tid];
      int ok = (v >= 0 && v < N_NODES);
      unsigned long long m = __ballot(ok);
      if (tid == 0) *flag = (m == ~0ull) ? 1 : 0;
    }
  } else if (b <= 49) {
    ((int4*)cnt)[(b - 1) * 256 + tid] = make_int4(0, 0, 0, 0);
  } else {
    int j = (b - 50) * 256 + tid;           // [0, 21504)
    if (j < 128 * 128) {
      int o = j >> 7, k = j & 127;
      Wt1[k * 128 + o] = W1[j];
    } else {
      int jj = j - 128 * 128;               // [0, 5120)
      int c = jj >> 7, k = jj & 127;
      Wt2[k * 40 + c] = W2[jj];
    }
  }
}

// ---------------------------------------------------------------------------
// CSR build: histogram by dst -> 3-phase coalesced scan -> slot scatter
// ---------------------------------------------------------------------------
__global__ __launch_bounds__(256) void hist_kernel(const void* __restrict__ ei,
                                                   const int* __restrict__ flag,
                                                   int* __restrict__ cnt) {
  int e = blockIdx.x * 256 + threadIdx.x;
  if (e >= N_EDGES) return;
  int dst = load_idx(ei, *flag, (long long)N_EDGES + e);
  atomicAdd(&cnt[dst], 1);
}

__global__ __launch_bounds__(256) void scanA_kernel(const int* __restrict__ cnt,
                                                    int* __restrict__ bsum) {
  __shared__ int sdata[256];
  int tid = threadIdx.x;
  const int4* c4 = (const int4*)cnt;
  int4 v = c4[blockIdx.x * 256 + tid];
  sdata[tid] = v.x + v.y + v.z + v.w;
  __syncthreads();
  #pragma unroll
  for (int off = 128; off > 0; off >>= 1) {
    if (tid < off) sdata[tid] += sdata[tid + off];
    __syncthreads();
  }
  if (tid == 0) bsum[blockIdx.x] = sdata[0];
}

__global__ void scanB_kernel(const int* __restrict__ bsum,
                             int* __restrict__ boff,
                             int* __restrict__ rowptr) {
  __shared__ int s[SCAN_NB];
  int tid = threadIdx.x;
  if (tid < SCAN_NB) s[tid] = bsum[tid];
  __syncthreads();
  if (tid == 0) {
    int acc = 0;
    for (int i = 0; i < SCAN_NB; ++i) { int t = s[i]; s[i] = acc; acc += t; }
    rowptr[N_NODES] = acc;
  }
  __syncthreads();
  if (tid < SCAN_NB) boff[tid] = s[tid];
}

__global__ __launch_bounds__(256) void scanC_kernel(const int* __restrict__ cnt,
                                                    const int* __restrict__ boff,
                                                    int* __restrict__ rowptr,
                                                    int* __restrict__ cursor) {
  __shared__ int sdata[256];
  int tid = threadIdx.x;
  const int4* c4 = (const int4*)cnt;
  int4 v = c4[blockIdx.x * 256 + tid];
  int s = v.x + v.y + v.z + v.w;
  sdata[tid] = s;
  __syncthreads();
  #pragma unroll
  for (int off = 1; off < 256; off <<= 1) {
    int t = (tid >= off) ? sdata[tid - off] : 0;
    __syncthreads();
    sdata[tid] += t;
    __syncthreads();
  }
  int excl = ((tid == 0) ? 0 : sdata[tid - 1]) + boff[blockIdx.x];
  int p0 = excl, p1 = p0 + v.x, p2 = p1 + v.y, p3 = p2 + v.z;
  int idx = blockIdx.x * SCAN_BLK + tid * 4;
  int4 r = make_int4(p0, p1, p2, p3);
  if (idx + 3 < N_NODES) {
    ((int4*)rowptr)[idx >> 2] = r;
    ((int4*)cursor)[idx >> 2] = r;
  } else {
    int p[4] = {p0, p1, p2, p3};
    #pragma unroll
    for (int j = 0; j < 4; ++j)
      if (idx + j < N_NODES) { rowptr[idx + j] = p[j]; cursor[idx + j] = p[j]; }
  }
}

__global__ __launch_bounds__(256) void scatter_kernel(const void* __restrict__ ei,
                                                      const int* __restrict__ flag,
                                                      int* __restrict__ cursor,
                                                      int* __restrict__ col) {
  int e = blockIdx.x * 256 + threadIdx.x;
  if (e >= N_EDGES) return;
  int f = *flag;
  int src = load_idx(ei, f, e);
  int dst = load_idx(ei, f, (long long)N_EDGES + e);
  int slot = atomicAdd(&cursor[dst], 1);
  col[slot] = src;
}

// ---------------------------------------------------------------------------
// gather1: h1[n] = relu(Y[n] + sum_src Y[src]), 128 floats/row.
// One wave/node; lane-halves (32 lanes, float4 each) take even/odd edges.
// ---------------------------------------------------------------------------
__global__ __launch_bounds__(256) void gather1_kernel(const float* __restrict__ Y,
                                                      const int* __restrict__ rowptr,
                                                      const int* __restrict__ col,
                                                      float* __restrict__ h1) {
  int w = (blockIdx.x * 256 + threadIdx.x) >> 6;
  if (w >= N_NODES) return;
  int lane = threadIdx.x & 63;
  int h = lane >> 5;        // half 0/1
  int q = lane & 31;        // float4 slot
  const float4* Y4 = (const float4*)Y;
  float4 acc = make_float4(0.f, 0.f, 0.f, 0.f);
  if (h == 0) acc = Y4[(size_t)w * 32 + q];
  int i = rowptr[w] + h, end = rowptr[w + 1];
  for (; i + 6 < end; i += 8) {
    int s0 = col[i], s1 = col[i + 2], s2 = col[i + 4], s3 = col[i + 6];
    float4 v0 = Y4[(size_t)s0 * 32 + q];
    float4 v1 = Y4[(size_t)s1 * 32 + q];
    float4 v2 = Y4[(size_t)s2 * 32 + q];
    float4 v3 = Y4[(size_t)s3 * 32 + q];
    acc.x += (v0.x + v1.x) + (v2.x + v3.x);
    acc.y += (v0.y + v1.y) + (v2.y + v3.y);
    acc.z += (v0.z + v1.z) + (v2.z + v3.z);
    acc.w += (v0.w + v1.w) + (v2.w + v3.w);
  }
  for (; i < end; i += 2) {
    int s0 = col[i];
    float4 v0 = Y4[(size_t)s0 * 32 + q];
    acc.x += v0.x; acc.y += v0.y; acc.z += v0.z; acc.w += v0.w;
  }
  acc.x += __shfl_xor(acc.x, 32);
  acc.y += __shfl_xor(acc.y, 32);
  acc.z += __shfl_xor(acc.z, 32);
  acc.w += __shfl_xor(acc.w, 32);
  if (h == 0) {
    float4 r;
    r.x = fmaxf(acc.x, 0.f); r.y = fmaxf(acc.y, 0.f);
    r.z = fmaxf(acc.z, 0.f); r.w = fmaxf(acc.w, 0.f);
    ((float4*)h1)[(size_t)w * 32 + q] = r;
  }
}

// ---------------------------------------------------------------------------
// gather2: out[n] = Z[n] + sum_src Z[src], 40 floats/row (10 float4).
// One wave/node; lane-quarters (16 lanes, q<10 active) take edges i, i+4, ...
// ---------------------------------------------------------------------------
__global__ __launch_bounds__(256) void gather2_kernel(const float* __restrict__ Z,
                                                      const int* __restrict__ rowptr,
                                                      const int* __restrict__ col,
                                                      float* __restrict__ outp) {
  int w = (blockIdx.x * 256 + threadIdx.x) >> 6;
  if (w >= N_NODES) return;
  int lane = threadIdx.x & 63;
  int h = lane >> 4;        // quarter 0..3
  int q = lane & 15;        // float4 slot, active q<10
  bool act = q < 10;
  const float4* Z4 = (const float4*)Z;
  float4 acc = make_float4(0.f, 0.f, 0.f, 0.f);
  if (h == 0 && act) acc = Z4[(size_t)w * 10 + q];
  int i = rowptr[w] + h, end = rowptr[w + 1];
  for (; i + 4 < end; i += 8) {
    int s0 = col[i], s1 = col[i + 4];
    if (act) {
      float4 v0 = Z4[(size_t)s0 * 10 + q];
      float4 v1 = Z4[(size_t)s1 * 10 + q];
      acc.x += v0.x + v1.x; acc.y += v0.y + v1.y;
      acc.z += v0.z + v1.z; acc.w += v0.w + v1.w;
    }
  }
  for (; i < end; i += 4) {
    int s0 = col[i];
    if (act) {
      float4 v0 = Z4[(size_t)s0 * 10 + q];
      acc.x += v0.x; acc.y += v0.y; acc.z += v0.z; acc.w += v0.w;
    }
  }
  acc.x += __shfl_xor(acc.x, 16);
  acc.y += __shfl_xor(acc.y, 16);
  acc.z += __shfl_xor(acc.z, 16);
  acc.w += __shfl_xor(acc.w, 16);
  acc.x += __shfl_xor(acc.x, 32);
  acc.y += __shfl_xor(acc.y, 32);
  acc.z += __shfl_xor(acc.z, 32);
  acc.w += __shfl_xor(acc.w, 32);
  if (h == 0 && act)
    ((float4*)outp)[(size_t)w * 10 + q] = acc;
}

#define FMA4(acc, h, w0, w1, w2, w3)                                               \
  acc.x = fmaf(h.x, w0.x, acc.x); acc.x = fmaf(h.y, w1.x, acc.x);                  \
  acc.x = fmaf(h.z, w2.x, acc.x); acc.x = fmaf(h.w, w3.x, acc.x);                  \
  acc.y = fmaf(h.x, w0.y, acc.y); acc.y = fmaf(h.y, w1.y, acc.y);                  \
  acc.y = fmaf(h.z, w2.y, acc.y); acc.y = fmaf(h.w, w3.y, acc.y);                  \
  acc.z = fmaf(h.x, w0.z, acc.z); acc.z = fmaf(h.y, w1.z, acc.z);                  \
  acc.z = fmaf(h.z, w2.z, acc.z); acc.z = fmaf(h.w, w3.z, acc.z);                  \
  acc.w = fmaf(h.x, w0.w, acc.w); acc.w = fmaf(h.y, w1.w, acc.w);                  \
  acc.w = fmaf(h.z, w2.w, acc.w); acc.w = fmaf(h.w, w3.w, acc.w);

// ---------------------------------------------------------------------------
// GEMM1: Y[n][o] = sum_k x[n][k] * W1[o][k]  (no relu; relu fused in gather1)
// ---------------------------------------------------------------------------
__global__ __launch_bounds__(256) void gemm1_kernel(const float* __restrict__ xin,
                                                    const float* __restrict__ Wt,
                                                    float* __restrict__ Y) {
  __shared__ float4 Hs[64 * 32];
  int tid = threadIdx.x;
  int n0 = blockIdx.x * 64;
  const float4* hp4 = (const float4*)xin;
  #pragma unroll
  for (int it = 0; it < 8; ++it) {
    int i = tid + it * 256;
    int r = i >> 5, k4 = i & 31;
    int n = n0 + r;
    float4 v = make_float4(0.f, 0.f, 0.f, 0.f);
    if (n < N_NODES) v = hp4[(size_t)n * 32 + k4];
    Hs[i] = v;
  }
  __syncthreads();
  int o4 = tid & 31;
  int r0 = (tid >> 5) * 8;
  float4 acc[8];
  #pragma unroll
  for (int j = 0; j < 8; ++j) acc[j] = make_float4(0.f, 0.f, 0.f, 0.f);
  const float4* Wt4 = (const float4*)Wt;
  #pragma unroll 4
  for (int k4 = 0; k4 < 32; ++k4) {
    float4 w0 = Wt4[(k4 * 4 + 0) * 32 + o4];
    float4 w1 = Wt4[(k4 * 4 + 1) * 32 + o4];
    float4 w2 = Wt4[(k4 * 4 + 2) * 32 + o4];
    float4 w3 = Wt4[(k4 * 4 + 3) * 32 + o4];
    #pragma unroll
    for (int j = 0; j < 8; ++j) {
      float4 h = Hs[(r0 + j) * 32 + k4];
      FMA4(acc[j], h, w0, w1, w2, w3);
    }
  }
  float4* out4 = (float4*)Y;
  #pragma unroll
  for (int j = 0; j < 8; ++j) {
    int n = n0 + r0 + j;
    if (n < N_NODES) out4[(size_t)n * 32 + o4] = acc[j];
  }
}

// ---------------------------------------------------------------------------
// GEMM2: Z[n][c] = sum_k h1[n][k] * W2[c][k], c < 40.
// ---------------------------------------------------------------------------
__global__ __launch_bounds__(320) void gemm2_kernel(const float* __restrict__ h1,
                                                    const float* __restrict__ Wt2,
                                                    float* __restrict__ Z) {
  __shared__ float4 Hs[64 * 33];
  int tid = threadIdx.x;
  int n0 = blockIdx.x * 64;
  const float4* hp4 = (const float4*)h1;
  for (int i = tid; i < 64 * 32; i += 320) {
    int r = i >> 5, k4 = i & 31;
    int n = n0 + r;
    float4 v = make_float4(0.f, 0.f, 0.f, 0.f);
    if (n < N_NODES) v = hp4[(size_t)n * 32 + k4];
    Hs[r * 33 + k4] = v;
  }
  __syncthreads();
  int cg = tid % 10;
  int r0 = (tid / 10) * 2;
  float4 acc0 = make_float4(0.f, 0.f, 0.f, 0.f);
  float4 acc1 = make_float4(0.f, 0.f, 0.f, 0.f);
  const float4* Wt4 = (const float4*)Wt2;
  #pragma unroll 4
  for (int k4 = 0; k4 < 32; ++k4) {
    float4 w0 = Wt4[(k4 * 4 + 0) * 10 + cg];
    float4 w1 = Wt4[(k4 * 4 + 1) * 10 + cg];
    float4 w2 = Wt4[(k4 * 4 + 2) * 10 + cg];
    float4 w3 = Wt4[(k4 * 4 + 3) * 10 + cg];
    float4 h0 = Hs[(r0    ) * 33 + k4];
    float4 h1v = Hs[(r0 + 1) * 33 + k4];
    FMA4(acc0, h0, w0, w1, w2, w3);
    FMA4(acc1, h1v, w0, w1, w2, w3);
  }
  int n = n0 + r0;
  float4* o4p = (float4*)Z;
  if (n < N_NODES)     o4p[(size_t)n * 10 + cg] = acc0;
  if (n + 1 < N_NODES) o4p[(size_t)(n + 1) * 10 + cg] = acc1;
}

// ---------------------------------------------------------------------------
extern "C" void kernel_launch(void* const* d_in, const int* in_sizes, int n_in,
                              void* d_out, int out_size, void* d_ws, size_t ws_size,
                              hipStream_t stream) {
  const float* x  = (const float*)d_in[0];
  const void*  ei = d_in[1];
  const float* W1 = (const float*)d_in[2];
  const float* W2 = (const float*)d_in[3];
  float* out = (float*)d_out;

  // ws layout (4-byte units)
  int* cnt    = (int*)d_ws;                 // CNT_PAD
  int* rowptr = cnt + CNT_PAD;
  int* cursor = rowptr + CNT_PAD;
  int* col    = cursor + CNT_PAD;           // 800000
  int* flag   = col + N_EDGES;              // +16 pad
  int* bsum   = flag + 16;                  // 64
  int* boff   = bsum + 64;                  // 64
  float* Y    = (float*)(boff + 64);        // 6.4M floats (16B aligned)
  float* h1   = Y + (size_t)N_NODES * 128;  // 6.4M floats
  float* Wt1  = h1 + (size_t)N_NODES * 128; // 16384
  float* Wt2  = Wt1 + 128 * 128;            // 5120
  float* Z    = Y;                          // Z (2M floats) reuses dead Y region

  prep_kernel<<<134, 256, 0, stream>>>(ei, W1, W2, flag, cnt, Wt1, Wt2);
  hist_kernel<<<(N_EDGES + 255) / 256, 256, 0, stream>>>(ei, flag, cnt);
  scanA_kernel<<<SCAN_NB, 256, 0, stream>>>(cnt, bsum);
  scanB_kernel<<<1, 64, 0, stream>>>(bsum, boff, rowptr);
  scanC_kernel<<<SCAN_NB, 256, 0, stream>>>(cnt, boff, rowptr, cursor);
  scatter_kernel<<<(N_EDGES + 255) / 256, 256, 0, stream>>>(ei, flag, cursor, col);

  // Layer 1 (commuted): Y = x @ W1^T ; h1 = relu(Y + A*Y)
  gemm1_kernel<<<(N_NODES + 63) / 64, 256, 0, stream>>>(x, Wt1, Y);
  gather1_kernel<<<(N_NODES * 64) / 256, 256, 0, stream>>>(Y, rowptr, col, h1);

  // Layer 2 (commuted): Z = h1 @ W2^T ; out = Z + A*Z
  gemm2_kernel<<<(N_NODES + 63) / 64, 320, 0, stream>>>(h1, Wt2, Z);
  gather2_kernel<<<(N_NODES * 64) / 256, 256, 0, stream>>>(Z, rowptr, col, out);
}

// Round 4
// 234.727 us; speedup vs baseline: 1.7538x; 1.1419x over previous
//
#include <hip/hip_runtime.h>

#define N_NODES 50000
#define N_EDGES 800000
#define SCAN_BLK 1024
#define SCAN_NB  ((N_NODES + SCAN_BLK - 1) / SCAN_BLK)   // 49
#define CNT_PAD  (SCAN_NB * SCAN_BLK)                    // 50176

__device__ __forceinline__ int load_idx(const void* ei, int is64, long long pos) {
  return is64 ? (int)((const long long*)ei)[pos] : ((const int*)ei)[pos];
}

// bf16 (RNE) pack/unpack helpers
__device__ __forceinline__ unsigned bfr(float f) {
  unsigned u = __float_as_uint(f);
  return (u + 0x7FFFu + ((u >> 16) & 1u)) >> 16;
}
__device__ __forceinline__ unsigned bfpk(float lo, float hi) {
  return bfr(lo) | (bfr(hi) << 16);
}
// unpack uint2 (4 bf16) and add into float4 accumulator
#define ACC_BF4(acc, u)                                                    \
  acc.x += __uint_as_float((u).x << 16);                                   \
  acc.y += __uint_as_float((u).x & 0xffff0000u);                           \
  acc.z += __uint_as_float((u).y << 16);                                   \
  acc.w += __uint_as_float((u).y & 0xffff0000u);

// ---------------------------------------------------------------------------
// prep: block 0 = dtype detect; blocks 1..49 zero cnt (int4); blocks 50..133
// transpose W1->Wt1 [k][o] and W2->Wt2 [k][c].
// ---------------------------------------------------------------------------
__global__ __launch_bounds__(256) void prep_kernel(const void* __restrict__ ei,
                                                   const float* __restrict__ W1,
                                                   const float* __restrict__ W2,
                                                   int* __restrict__ flag,
                                                   int* __restrict__ cnt,
                                                   float* __restrict__ Wt1,
                                                   float* __restrict__ Wt2) {
  int b = blockIdx.x, tid = threadIdx.x;
  if (b == 0) {
    if (tid < 64) {
      const long long* e64 = (const long long*)ei;
      long long v = e64[tid];
      int ok = (v >= 0 && v < N_NODES);
      unsigned long long m = __ballot(ok);
      if (tid == 0) *flag = (m == ~0ull) ? 1 : 0;
    }
  } else if (b <= 49) {
    ((int4*)cnt)[(b - 1) * 256 + tid] = make_int4(0, 0, 0, 0);
  } else {
    int j = (b - 50) * 256 + tid;           // [0, 21504)
    if (j < 128 * 128) {
      int o = j >> 7, k = j & 127;
      Wt1[k * 128 + o] = W1[j];
    } else {
      int jj = j - 128 * 128;               // [0, 5120)
      int c = jj >> 7, k = jj & 127;
      Wt2[k * 40 + c] = W2[jj];
    }
  }
}

// ---------------------------------------------------------------------------
// CSR build: histogram by dst -> 3-phase coalesced scan -> slot scatter
// ---------------------------------------------------------------------------
__global__ __launch_bounds__(256) void hist_kernel(const void* __restrict__ ei,
                                                   const int* __restrict__ flag,
                                                   int* __restrict__ cnt) {
  int e = blockIdx.x * 256 + threadIdx.x;
  if (e >= N_EDGES) return;
  int dst = load_idx(ei, *flag, (long long)N_EDGES + e);
  atomicAdd(&cnt[dst], 1);
}

__global__ __launch_bounds__(256) void scanA_kernel(const int* __restrict__ cnt,
                                                    int* __restrict__ bsum) {
  __shared__ int sdata[256];
  int tid = threadIdx.x;
  const int4* c4 = (const int4*)cnt;
  int4 v = c4[blockIdx.x * 256 + tid];
  sdata[tid] = v.x + v.y + v.z + v.w;
  __syncthreads();
  #pragma unroll
  for (int off = 128; off > 0; off >>= 1) {
    if (tid < off) sdata[tid] += sdata[tid + off];
    __syncthreads();
  }
  if (tid == 0) bsum[blockIdx.x] = sdata[0];
}

__global__ void scanB_kernel(const int* __restrict__ bsum,
                             int* __restrict__ boff,
                             int* __restrict__ rowptr) {
  __shared__ int s[SCAN_NB];
  int tid = threadIdx.x;
  if (tid < SCAN_NB) s[tid] = bsum[tid];
  __syncthreads();
  if (tid == 0) {
    int acc = 0;
    for (int i = 0; i < SCAN_NB; ++i) { int t = s[i]; s[i] = acc; acc += t; }
    rowptr[N_NODES] = acc;
  }
  __syncthreads();
  if (tid < SCAN_NB) boff[tid] = s[tid];
}

__global__ __launch_bounds__(256) void scanC_kernel(const int* __restrict__ cnt,
                                                    const int* __restrict__ boff,
                                                    int* __restrict__ rowptr,
                                                    int* __restrict__ cursor) {
  __shared__ int sdata[256];
  int tid = threadIdx.x;
  const int4* c4 = (const int4*)cnt;
  int4 v = c4[blockIdx.x * 256 + tid];
  int s = v.x + v.y + v.z + v.w;
  sdata[tid] = s;
  __syncthreads();
  #pragma unroll
  for (int off = 1; off < 256; off <<= 1) {
    int t = (tid >= off) ? sdata[tid - off] : 0;
    __syncthreads();
    sdata[tid] += t;
    __syncthreads();
  }
  int excl = ((tid == 0) ? 0 : sdata[tid - 1]) + boff[blockIdx.x];
  int p0 = excl, p1 = p0 + v.x, p2 = p1 + v.y, p3 = p2 + v.z;
  int idx = blockIdx.x * SCAN_BLK + tid * 4;
  int4 r = make_int4(p0, p1, p2, p3);
  if (idx + 3 < N_NODES) {
    ((int4*)rowptr)[idx >> 2] = r;
    ((int4*)cursor)[idx >> 2] = r;
  } else {
    int p[4] = {p0, p1, p2, p3};
    #pragma unroll
    for (int j = 0; j < 4; ++j)
      if (idx + j < N_NODES) { rowptr[idx + j] = p[j]; cursor[idx + j] = p[j]; }
  }
}

__global__ __launch_bounds__(256) void scatter_kernel(const void* __restrict__ ei,
                                                      const int* __restrict__ flag,
                                                      int* __restrict__ cursor,
                                                      int* __restrict__ col) {
  int e = blockIdx.x * 256 + threadIdx.x;
  if (e >= N_EDGES) return;
  int f = *flag;
  int src = load_idx(ei, f, e);
  int dst = load_idx(ei, f, (long long)N_EDGES + e);
  int slot = atomicAdd(&cursor[dst], 1);
  col[slot] = src;
}

// ---------------------------------------------------------------------------
// gather1: h1[n] = relu(Y[n] + sum_src Y[src]); Y is bf16, 128/row (32 uint2).
// One wave/node; halves (32 lanes x uint2 = 256B row) take even/odd edges.
// ---------------------------------------------------------------------------
__global__ __launch_bounds__(256) void gather1_kernel(const unsigned short* __restrict__ Ybf,
                                                      const int* __restrict__ rowptr,
                                                      const int* __restrict__ col,
                                                      float* __restrict__ h1) {
  int w = (blockIdx.x * 256 + threadIdx.x) >> 6;
  if (w >= N_NODES) return;
  int lane = threadIdx.x & 63;
  int h = lane >> 5;        // half 0/1
  int q = lane & 31;        // uint2 slot (4 bf16 = elems 4q..4q+3)
  const uint2* Y2 = (const uint2*)Ybf;   // row = 32 uint2
  float4 acc = make_float4(0.f, 0.f, 0.f, 0.f);
  if (h == 0) {
    uint2 u = Y2[(size_t)w * 32 + q];
    ACC_BF4(acc, u);
  }
  int i = rowptr[w] + h, end = rowptr[w + 1];
  for (; i + 6 < end; i += 8) {
    int s0 = col[i], s1 = col[i + 2], s2 = col[i + 4], s3 = col[i + 6];
    uint2 u0 = Y2[(size_t)s0 * 32 + q];
    uint2 u1 = Y2[(size_t)s1 * 32 + q];
    uint2 u2 = Y2[(size_t)s2 * 32 + q];
    uint2 u3 = Y2[(size_t)s3 * 32 + q];
    ACC_BF4(acc, u0); ACC_BF4(acc, u1); ACC_BF4(acc, u2); ACC_BF4(acc, u3);
  }
  for (; i < end; i += 2) {
    uint2 u0 = Y2[(size_t)col[i] * 32 + q];
    ACC_BF4(acc, u0);
  }
  acc.x += __shfl_xor(acc.x, 32);
  acc.y += __shfl_xor(acc.y, 32);
  acc.z += __shfl_xor(acc.z, 32);
  acc.w += __shfl_xor(acc.w, 32);
  if (h == 0) {
    float4 r;
    r.x = fmaxf(acc.x, 0.f); r.y = fmaxf(acc.y, 0.f);
    r.z = fmaxf(acc.z, 0.f); r.w = fmaxf(acc.w, 0.f);
    ((float4*)h1)[(size_t)w * 32 + q] = r;
  }
}

// ---------------------------------------------------------------------------
// gather2: out[n] = Z[n] + sum_src Z[src]; Z is bf16, 40/row (10 uint2, 80B).
// One wave/node; quarters (16 lanes, q<10 active) take edges i, i+4, ...
// ---------------------------------------------------------------------------
__global__ __launch_bounds__(256) void gather2_kernel(const unsigned short* __restrict__ Zbf,
                                                      const int* __restrict__ rowptr,
                                                      const int* __restrict__ col,
                                                      float* __restrict__ outp) {
  int w = (blockIdx.x * 256 + threadIdx.x) >> 6;
  if (w >= N_NODES) return;
  int lane = threadIdx.x & 63;
  int h = lane >> 4;        // quarter 0..3
  int q = lane & 15;        // uint2 slot, active q<10
  bool act = q < 10;
  const uint2* Z2 = (const uint2*)Zbf;   // row = 10 uint2
  float4 acc = make_float4(0.f, 0.f, 0.f, 0.f);
  if (h == 0 && act) {
    uint2 u = Z2[(size_t)w * 10 + q];
    ACC_BF4(acc, u);
  }
  int i = rowptr[w] + h, end = rowptr[w + 1];
  for (; i + 4 < end; i += 8) {
    int s0 = col[i], s1 = col[i + 4];
    if (act) {
      uint2 u0 = Z2[(size_t)s0 * 10 + q];
      uint2 u1 = Z2[(size_t)s1 * 10 + q];
      ACC_BF4(acc, u0); ACC_BF4(acc, u1);
    }
  }
  for (; i < end; i += 4) {
    int s0 = col[i];
    if (act) {
      uint2 u0 = Z2[(size_t)s0 * 10 + q];
      ACC_BF4(acc, u0);
    }
  }
  acc.x += __shfl_xor(acc.x, 16);
  acc.y += __shfl_xor(acc.y, 16);
  acc.z += __shfl_xor(acc.z, 16);
  acc.w += __shfl_xor(acc.w, 16);
  acc.x += __shfl_xor(acc.x, 32);
  acc.y += __shfl_xor(acc.y, 32);
  acc.z += __shfl_xor(acc.z, 32);
  acc.w += __shfl_xor(acc.w, 32);
  if (h == 0 && act)
    ((float4*)outp)[(size_t)w * 10 + q] = acc;
}

#define FMA4(acc, h, w0, w1, w2, w3)                                               \
  acc.x = fmaf(h.x, w0.x, acc.x); acc.x = fmaf(h.y, w1.x, acc.x);                  \
  acc.x = fmaf(h.z, w2.x, acc.x); acc.x = fmaf(h.w, w3.x, acc.x);                  \
  acc.y = fmaf(h.x, w0.y, acc.y); acc.y = fmaf(h.y, w1.y, acc.y);                  \
  acc.y = fmaf(h.z, w2.y, acc.y); acc.y = fmaf(h.w, w3.y, acc.y);                  \
  acc.z = fmaf(h.x, w0.z, acc.z); acc.z = fmaf(h.y, w1.z, acc.z);                  \
  acc.z = fmaf(h.z, w2.z, acc.z); acc.z = fmaf(h.w, w3.z, acc.z);                  \
  acc.w = fmaf(h.x, w0.w, acc.w); acc.w = fmaf(h.y, w1.w, acc.w);                  \
  acc.w = fmaf(h.z, w2.w, acc.w); acc.w = fmaf(h.w, w3.w, acc.w);

// ---------------------------------------------------------------------------
// GEMM1: Y[n][o] = sum_k x[n][k] * W1[o][k]; writes Y as bf16 (RNE).
// ---------------------------------------------------------------------------
__global__ __launch_bounds__(256) void gemm1_kernel(const float* __restrict__ xin,
                                                    const float* __restrict__ Wt,
                                                    unsigned short* __restrict__ Ybf) {
  __shared__ float4 Hs[64 * 32];
  int tid = threadIdx.x;
  int n0 = blockIdx.x * 64;
  const float4* hp4 = (const float4*)xin;
  #pragma unroll
  for (int it = 0; it < 8; ++it) {
    int i = tid + it * 256;
    int r = i >> 5, k4 = i & 31;
    int n = n0 + r;
    float4 v = make_float4(0.f, 0.f, 0.f, 0.f);
    if (n < N_NODES) v = hp4[(size_t)n * 32 + k4];
    Hs[i] = v;
  }
  __syncthreads();
  int o4 = tid & 31;
  int r0 = (tid >> 5) * 8;
  float4 acc[8];
  #pragma unroll
  for (int j = 0; j < 8; ++j) acc[j] = make_float4(0.f, 0.f, 0.f, 0.f);
  const float4* Wt4 = (const float4*)Wt;
  #pragma unroll 4
  for (int k4 = 0; k4 < 32; ++k4) {
    float4 w0 = Wt4[(k4 * 4 + 0) * 32 + o4];
    float4 w1 = Wt4[(k4 * 4 + 1) * 32 + o4];
    float4 w2 = Wt4[(k4 * 4 + 2) * 32 + o4];
    float4 w3 = Wt4[(k4 * 4 + 3) * 32 + o4];
    #pragma unroll
    for (int j = 0; j < 8; ++j) {
      float4 h = Hs[(r0 + j) * 32 + k4];
      FMA4(acc[j], h, w0, w1, w2, w3);
    }
  }
  uint2* out2 = (uint2*)Ybf;   // row = 32 uint2
  #pragma unroll
  for (int j = 0; j < 8; ++j) {
    int n = n0 + r0 + j;
    if (n < N_NODES) {
      float4 v = acc[j];
      uint2 p;
      p.x = bfpk(v.x, v.y);
      p.y = bfpk(v.z, v.w);
      out2[(size_t)n * 32 + o4] = p;
    }
  }
}

// ---------------------------------------------------------------------------
// GEMM2: Z[n][c] = sum_k h1[n][k] * W2[c][k], c < 40; writes Z as bf16.
// ---------------------------------------------------------------------------
__global__ __launch_bounds__(320) void gemm2_kernel(const float* __restrict__ h1,
                                                    const float* __restrict__ Wt2,
                                                    unsigned short* __restrict__ Zbf) {
  __shared__ float4 Hs[64 * 33];
  int tid = threadIdx.x;
  int n0 = blockIdx.x * 64;
  const float4* hp4 = (const float4*)h1;
  for (int i = tid; i < 64 * 32; i += 320) {
    int r = i >> 5, k4 = i & 31;
    int n = n0 + r;
    float4 v = make_float4(0.f, 0.f, 0.f, 0.f);
    if (n < N_NODES) v = hp4[(size_t)n * 32 + k4];
    Hs[r * 33 + k4] = v;
  }
  __syncthreads();
  int cg = tid % 10;
  int r0 = (tid / 10) * 2;
  float4 acc0 = make_float4(0.f, 0.f, 0.f, 0.f);
  float4 acc1 = make_float4(0.f, 0.f, 0.f, 0.f);
  const float4* Wt4 = (const float4*)Wt2;
  #pragma unroll 4
  for (int k4 = 0; k4 < 32; ++k4) {
    float4 w0 = Wt4[(k4 * 4 + 0) * 10 + cg];
    float4 w1 = Wt4[(k4 * 4 + 1) * 10 + cg];
    float4 w2 = Wt4[(k4 * 4 + 2) * 10 + cg];
    float4 w3 = Wt4[(k4 * 4 + 3) * 10 + cg];
    float4 h0 = Hs[(r0    ) * 33 + k4];
    float4 h1v = Hs[(r0 + 1) * 33 + k4];
    FMA4(acc0, h0, w0, w1, w2, w3);
    FMA4(acc1, h1v, w0, w1, w2, w3);
  }
  int n = n0 + r0;
  uint2* o2p = (uint2*)Zbf;   // row = 10 uint2
  if (n < N_NODES) {
    uint2 p; p.x = bfpk(acc0.x, acc0.y); p.y = bfpk(acc0.z, acc0.w);
    o2p[(size_t)n * 10 + cg] = p;
  }
  if (n + 1 < N_NODES) {
    uint2 p; p.x = bfpk(acc1.x, acc1.y); p.y = bfpk(acc1.z, acc1.w);
    o2p[(size_t)(n + 1) * 10 + cg] = p;
  }
}

// ---------------------------------------------------------------------------
extern "C" void kernel_launch(void* const* d_in, const int* in_sizes, int n_in,
                              void* d_out, int out_size, void* d_ws, size_t ws_size,
                              hipStream_t stream) {
  const float* x  = (const float*)d_in[0];
  const void*  ei = d_in[1];
  const float* W1 = (const float*)d_in[2];
  const float* W2 = (const float*)d_in[3];
  float* out = (float*)d_out;

  // ws layout (4-byte units)
  int* cnt    = (int*)d_ws;                 // CNT_PAD
  int* rowptr = cnt + CNT_PAD;
  int* cursor = rowptr + CNT_PAD;
  int* col    = cursor + CNT_PAD;           // 800000
  int* flag   = col + N_EDGES;              // +16 pad
  int* bsum   = flag + 16;                  // 64
  int* boff   = bsum + 64;                  // 64
  unsigned short* Ybf = (unsigned short*)(boff + 64);   // 6.4M bf16 (12.8MB), 16B aligned
  float* h1   = (float*)(Ybf + (size_t)N_NODES * 128);  // 6.4M floats
  float* Wt1  = h1 + (size_t)N_NODES * 128;             // 16384
  float* Wt2  = Wt1 + 128 * 128;                        // 5120
  unsigned short* Zbf = Ybf;                // Z (2M bf16) reuses dead Y region

  prep_kernel<<<134, 256, 0, stream>>>(ei, W1, W2, flag, cnt, Wt1, Wt2);
  hist_kernel<<<(N_EDGES + 255) / 256, 256, 0, stream>>>(ei, flag, cnt);
  scanA_kernel<<<SCAN_NB, 256, 0, stream>>>(cnt, bsum);
  scanB_kernel<<<1, 64, 0, stream>>>(bsum, boff, rowptr);
  scanC_kernel<<<SCAN_NB, 256, 0, stream>>>(cnt, boff, rowptr, cursor);
  scatter_kernel<<<(N_EDGES + 255) / 256, 256, 0, stream>>>(ei, flag, cursor, col);

  // Layer 1 (commuted): Y = x @ W1^T (bf16) ; h1 = relu(Y + A*Y) (f32)
  gemm1_kernel<<<(N_NODES + 63) / 64, 256, 0, stream>>>(x, Wt1, Ybf);
  gather1_kernel<<<(N_NODES * 64) / 256, 256, 0, stream>>>(Ybf, rowptr, col, h1);

  // Layer 2 (commuted): Z = h1 @ W2^T (bf16) ; out = Z + A*Z (f32)
  gemm2_kernel<<<(N_NODES + 63) / 64, 320, 0, stream>>>(h1, Wt2, Zbf);
  gather2_kernel<<<(N_NODES * 64) / 256, 256, 0, stream>>>(Zbf, rowptr, col, out);
}

// Round 5
// 177.165 us; speedup vs baseline: 2.3236x; 1.3249x over previous
//
#include <hip/hip_runtime.h>

#define N_NODES 50000
#define N_EDGES 800000
#define BSHIFT 6                                   // 64 nodes per bucket
#define NBKT   ((N_NODES + 63) >> BSHIFT)          // 782
#define CHUNK_EDGES 8192
#define NBIN_BLOCKS ((N_EDGES + CHUNK_EDGES - 1) / CHUNK_EDGES)  // 98

__device__ __forceinline__ int load_idx(const void* ei, int is64, long long pos) {
  return is64 ? (int)((const long long*)ei)[pos] : ((const int*)ei)[pos];
}

// bf16 (RNE) pack/unpack helpers
__device__ __forceinline__ unsigned bfr(float f) {
  unsigned u = __float_as_uint(f);
  return (u + 0x7FFFu + ((u >> 16) & 1u)) >> 16;
}
__device__ __forceinline__ unsigned bfpk(float lo, float hi) {
  return bfr(lo) | (bfr(hi) << 16);
}
#define ACC_BF4(acc, u)                                                    \
  acc.x += __uint_as_float((u).x << 16);                                   \
  acc.y += __uint_as_float((u).x & 0xffff0000u);                           \
  acc.z += __uint_as_float((u).y << 16);                                   \
  acc.w += __uint_as_float((u).y & 0xffff0000u);

// ---------------------------------------------------------------------------
// prep: block 0 = dtype detect; block 1 zeroes gtot; blocks 2..85 transpose W.
// ---------------------------------------------------------------------------
__global__ __launch_bounds__(256) void prep_kernel(const void* __restrict__ ei,
                                                   const float* __restrict__ W1,
                                                   const float* __restrict__ W2,
                                                   int* __restrict__ flag,
                                                   int* __restrict__ gtot,
                                                   float* __restrict__ Wt1,
                                                   float* __restrict__ Wt2) {
  int b = blockIdx.x, tid = threadIdx.x;
  if (b == 0) {
    if (tid < 64) {
      const long long* e64 = (const long long*)ei;
      long long v = e64[tid];
      int ok = (v >= 0 && v < N_NODES);
      unsigned long long m = __ballot(ok);
      if (tid == 0) *flag = (m == ~0ull) ? 1 : 0;
    }
  } else if (b == 1) {
    ((int4*)gtot)[tid] = make_int4(0, 0, 0, 0);   // 1024 ints
  } else {
    int j = (b - 2) * 256 + tid;                  // [0, 21504)
    if (j < 128 * 128) {
      int o = j >> 7, k = j & 127;
      Wt1[k * 128 + o] = W1[j];
    } else {
      int jj = j - 128 * 128;                     // [0, 5120)
      int c = jj >> 7, k = jj & 127;
      Wt2[k * 40 + c] = W2[jj];
    }
  }
}

// ---------------------------------------------------------------------------
// binCount: LDS-aggregated bucket histogram. 98 blocks x 8192 edges.
// ---------------------------------------------------------------------------
__global__ __launch_bounds__(256) void binCount_kernel(const void* __restrict__ ei,
                                                       const int* __restrict__ flag,
                                                       int* __restrict__ gtot) {
  __shared__ int cnt[NBKT];
  int tid = threadIdx.x;
  for (int i = tid; i < NBKT; i += 256) cnt[i] = 0;
  __syncthreads();
  int f = *flag;
  long long base = (long long)blockIdx.x * CHUNK_EDGES;
  #pragma unroll
  for (int it = 0; it < CHUNK_EDGES / 256; ++it) {
    long long e = base + it * 256 + tid;
    if (e < N_EDGES) {
      int dst = load_idx(ei, f, (long long)N_EDGES + e);
      atomicAdd(&cnt[dst >> BSHIFT], 1);
    }
  }
  __syncthreads();
  for (int i = tid; i < NBKT; i += 256) {
    int c = cnt[i];
    if (c) atomicAdd(&gtot[i], c);
  }
}

// ---------------------------------------------------------------------------
// bucketScan: exclusive scan of 782 bucket totals -> gbase/gcur.
// ---------------------------------------------------------------------------
__global__ __launch_bounds__(1024) void bucketScan_kernel(const int* __restrict__ gtot,
                                                          int* __restrict__ gbase,
                                                          int* __restrict__ gcur,
                                                          int* __restrict__ rowptr) {
  __shared__ int s[1024];
  int tid = threadIdx.x;
  s[tid] = (tid < NBKT) ? gtot[tid] : 0;
  __syncthreads();
  for (int off = 1; off < 1024; off <<= 1) {
    int t = (tid >= off) ? s[tid - off] : 0;
    __syncthreads();
    s[tid] += t;
    __syncthreads();
  }
  int excl = (tid == 0) ? 0 : s[tid - 1];
  if (tid < NBKT) { gbase[tid] = excl; gcur[tid] = excl; }
  if (tid == NBKT) gbase[NBKT] = s[NBKT - 1];   // == N_EDGES
  if (tid == 0) rowptr[N_NODES] = N_EDGES;
}

// ---------------------------------------------------------------------------
// binPlace: per-block LDS histogram -> one global reservation per bucket ->
// LDS cursors place packed edges. pk = src | dstlow<<16 | bucket<<22.
// ---------------------------------------------------------------------------
__global__ __launch_bounds__(256) void binPlace_kernel(const void* __restrict__ ei,
                                                       const int* __restrict__ flag,
                                                       int* __restrict__ gcur,
                                                       unsigned* __restrict__ binned) {
  __shared__ int cnt[NBKT];
  __shared__ int lcur[NBKT];
  int tid = threadIdx.x;
  for (int i = tid; i < NBKT; i += 256) cnt[i] = 0;
  __syncthreads();
  int f = *flag;
  long long base = (long long)blockIdx.x * CHUNK_EDGES;
  unsigned pk[CHUNK_EDGES / 256];
  #pragma unroll
  for (int it = 0; it < CHUNK_EDGES / 256; ++it) {
    long long e = base + it * 256 + tid;
    unsigned p = 0xFFFFFFFFu;
    if (e < N_EDGES) {
      int src = load_idx(ei, f, e);
      int dst = load_idx(ei, f, (long long)N_EDGES + e);
      int bk = dst >> BSHIFT;
      p = (unsigned)src | ((unsigned)(dst & 63) << 16) | ((unsigned)bk << 22);
      atomicAdd(&cnt[bk], 1);
    }
    pk[it] = p;
  }
  __syncthreads();
  for (int i = tid; i < NBKT; i += 256) {
    int c = cnt[i];
    lcur[i] = c ? atomicAdd(&gcur[i], c) : 0;
  }
  __syncthreads();
  #pragma unroll
  for (int it = 0; it < CHUNK_EDGES / 256; ++it) {
    unsigned p = pk[it];
    if (p != 0xFFFFFFFFu) {
      int bk = p >> 22;
      int slot = atomicAdd(&lcur[bk], 1);
      binned[slot] = p & 0x3FFFFFu;     // src | dstlow<<16
    }
  }
}

// ---------------------------------------------------------------------------
// csrBuild: one block per bucket (64 nodes). LDS node histogram + serial scan
// -> rowptr; then place col (ushort src) within the bucket's 2KB window.
// ---------------------------------------------------------------------------
__global__ __launch_bounds__(256) void csrBuild_kernel(const unsigned* __restrict__ binned,
                                                       const int* __restrict__ gbase,
                                                       int* __restrict__ rowptr,
                                                       unsigned short* __restrict__ col) {
  __shared__ int ncnt[64];
  __shared__ int ncur[64];
  int b = blockIdx.x, tid = threadIdx.x;
  int lo = gbase[b], hi = gbase[b + 1];
  if (tid < 64) ncnt[tid] = 0;
  __syncthreads();
  for (int i = lo + tid; i < hi; i += 256)
    atomicAdd(&ncnt[(binned[i] >> 16) & 63], 1);
  __syncthreads();
  if (tid == 0) {
    int acc = lo;
    #pragma unroll
    for (int j = 0; j < 64; ++j) { int c = ncnt[j]; ncur[j] = acc; acc += c; }
  }
  __syncthreads();
  int node0 = b << BSHIFT;
  if (tid < 64 && node0 + tid < N_NODES) rowptr[node0 + tid] = ncur[tid];
  __syncthreads();
  for (int i = lo + tid; i < hi; i += 256) {
    unsigned p = binned[i];
    int slot = atomicAdd(&ncur[(p >> 16) & 63], 1);
    col[slot] = (unsigned short)(p & 0xFFFFu);
  }
}

// ---------------------------------------------------------------------------
// gather1: h1[n] = relu(Y[n] + sum_src Y[src]); Y bf16, 128/row (32 uint2).
// ---------------------------------------------------------------------------
__global__ __launch_bounds__(256) void gather1_kernel(const unsigned short* __restrict__ Ybf,
                                                      const int* __restrict__ rowptr,
                                                      const unsigned short* __restrict__ col,
                                                      float* __restrict__ h1) {
  int w = (blockIdx.x * 256 + threadIdx.x) >> 6;
  if (w >= N_NODES) return;
  int lane = threadIdx.x & 63;
  int h = lane >> 5;
  int q = lane & 31;
  const uint2* Y2 = (const uint2*)Ybf;
  float4 acc = make_float4(0.f, 0.f, 0.f, 0.f);
  if (h == 0) {
    uint2 u = Y2[(size_t)w * 32 + q];
    ACC_BF4(acc, u);
  }
  int i = rowptr[w] + h, end = rowptr[w + 1];
  for (; i + 6 < end; i += 8) {
    int s0 = col[i], s1 = col[i + 2], s2 = col[i + 4], s3 = col[i + 6];
    uint2 u0 = Y2[(size_t)s0 * 32 + q];
    uint2 u1 = Y2[(size_t)s1 * 32 + q];
    uint2 u2 = Y2[(size_t)s2 * 32 + q];
    uint2 u3 = Y2[(size_t)s3 * 32 + q];
    ACC_BF4(acc, u0); ACC_BF4(acc, u1); ACC_BF4(acc, u2); ACC_BF4(acc, u3);
  }
  for (; i < end; i += 2) {
    uint2 u0 = Y2[(size_t)col[i] * 32 + q];
    ACC_BF4(acc, u0);
  }
  acc.x += __shfl_xor(acc.x, 32);
  acc.y += __shfl_xor(acc.y, 32);
  acc.z += __shfl_xor(acc.z, 32);
  acc.w += __shfl_xor(acc.w, 32);
  if (h == 0) {
    float4 r;
    r.x = fmaxf(acc.x, 0.f); r.y = fmaxf(acc.y, 0.f);
    r.z = fmaxf(acc.z, 0.f); r.w = fmaxf(acc.w, 0.f);
    ((float4*)h1)[(size_t)w * 32 + q] = r;
  }
}

// ---------------------------------------------------------------------------
// gather2: out[n] = Z[n] + sum_src Z[src]; Z bf16, 40/row (10 uint2).
// ---------------------------------------------------------------------------
__global__ __launch_bounds__(256) void gather2_kernel(const unsigned short* __restrict__ Zbf,
                                                      const int* __restrict__ rowptr,
                                                      const unsigned short* __restrict__ col,
                                                      float* __restrict__ outp) {
  int w = (blockIdx.x * 256 + threadIdx.x) >> 6;
  if (w >= N_NODES) return;
  int lane = threadIdx.x & 63;
  int h = lane >> 4;
  int q = lane & 15;
  bool act = q < 10;
  const uint2* Z2 = (const uint2*)Zbf;
  float4 acc = make_float4(0.f, 0.f, 0.f, 0.f);
  if (h == 0 && act) {
    uint2 u = Z2[(size_t)w * 10 + q];
    ACC_BF4(acc, u);
  }
  int i = rowptr[w] + h, end = rowptr[w + 1];
  for (; i + 4 < end; i += 8) {
    int s0 = col[i], s1 = col[i + 4];
    if (act) {
      uint2 u0 = Z2[(size_t)s0 * 10 + q];
      uint2 u1 = Z2[(size_t)s1 * 10 + q];
      ACC_BF4(acc, u0); ACC_BF4(acc, u1);
    }
  }
  for (; i < end; i += 4) {
    int s0 = col[i];
    if (act) {
      uint2 u0 = Z2[(size_t)s0 * 10 + q];
      ACC_BF4(acc, u0);
    }
  }
  acc.x += __shfl_xor(acc.x, 16);
  acc.y += __shfl_xor(acc.y, 16);
  acc.z += __shfl_xor(acc.z, 16);
  acc.w += __shfl_xor(acc.w, 16);
  acc.x += __shfl_xor(acc.x, 32);
  acc.y += __shfl_xor(acc.y, 32);
  acc.z += __shfl_xor(acc.z, 32);
  acc.w += __shfl_xor(acc.w, 32);
  if (h == 0 && act)
    ((float4*)outp)[(size_t)w * 10 + q] = acc;
}

#define FMA4(acc, h, w0, w1, w2, w3)                                               \
  acc.x = fmaf(h.x, w0.x, acc.x); acc.x = fmaf(h.y, w1.x, acc.x);                  \
  acc.x = fmaf(h.z, w2.x, acc.x); acc.x = fmaf(h.w, w3.x, acc.x);                  \
  acc.y = fmaf(h.x, w0.y, acc.y); acc.y = fmaf(h.y, w1.y, acc.y);                  \
  acc.y = fmaf(h.z, w2.y, acc.y); acc.y = fmaf(h.w, w3.y, acc.y);                  \
  acc.z = fmaf(h.x, w0.z, acc.z); acc.z = fmaf(h.y, w1.z, acc.z);                  \
  acc.z = fmaf(h.z, w2.z, acc.z); acc.z = fmaf(h.w, w3.z, acc.z);                  \
  acc.w = fmaf(h.x, w0.w, acc.w); acc.w = fmaf(h.y, w1.w, acc.w);                  \
  acc.w = fmaf(h.z, w2.w, acc.w); acc.w = fmaf(h.w, w3.w, acc.w);

// ---------------------------------------------------------------------------
// GEMM1: Y[n][o] = sum_k x[n][k] * W1[o][k]; writes Y as bf16 (RNE).
// ---------------------------------------------------------------------------
__global__ __launch_bounds__(256) void gemm1_kernel(const float* __restrict__ xin,
                                                    const float* __restrict__ Wt,
                                                    unsigned short* __restrict__ Ybf) {
  __shared__ float4 Hs[64 * 32];
  int tid = threadIdx.x;
  int n0 = blockIdx.x * 64;
  const float4* hp4 = (const float4*)xin;
  #pragma unroll
  for (int it = 0; it < 8; ++it) {
    int i = tid + it * 256;
    int r = i >> 5, k4 = i & 31;
    int n = n0 + r;
    float4 v = make_float4(0.f, 0.f, 0.f, 0.f);
    if (n < N_NODES) v = hp4[(size_t)n * 32 + k4];
    Hs[i] = v;
  }
  __syncthreads();
  int o4 = tid & 31;
  int r0 = (tid >> 5) * 8;
  float4 acc[8];
  #pragma unroll
  for (int j = 0; j < 8; ++j) acc[j] = make_float4(0.f, 0.f, 0.f, 0.f);
  const float4* Wt4 = (const float4*)Wt;
  #pragma unroll 4
  for (int k4 = 0; k4 < 32; ++k4) {
    float4 w0 = Wt4[(k4 * 4 + 0) * 32 + o4];
    float4 w1 = Wt4[(k4 * 4 + 1) * 32 + o4];
    float4 w2 = Wt4[(k4 * 4 + 2) * 32 + o4];
    float4 w3 = Wt4[(k4 * 4 + 3) * 32 + o4];
    #pragma unroll
    for (int j = 0; j < 8; ++j) {
      float4 h = Hs[(r0 + j) * 32 + k4];
      FMA4(acc[j], h, w0, w1, w2, w3);
    }
  }
  uint2* out2 = (uint2*)Ybf;
  #pragma unroll
  for (int j = 0; j < 8; ++j) {
    int n = n0 + r0 + j;
    if (n < N_NODES) {
      float4 v = acc[j];
      uint2 p;
      p.x = bfpk(v.x, v.y);
      p.y = bfpk(v.z, v.w);
      out2[(size_t)n * 32 + o4] = p;
    }
  }
}

// ---------------------------------------------------------------------------
// GEMM2: Z[n][c] = sum_k h1[n][k] * W2[c][k], c < 40; writes Z as bf16.
// ---------------------------------------------------------------------------
__global__ __launch_bounds__(320) void gemm2_kernel(const float* __restrict__ h1,
                                                    const float* __restrict__ Wt2,
                                                    unsigned short* __restrict__ Zbf) {
  __shared__ float4 Hs[64 * 33];
  int tid = threadIdx.x;
  int n0 = blockIdx.x * 64;
  const float4* hp4 = (const float4*)h1;
  for (int i = tid; i < 64 * 32; i += 320) {
    int r = i >> 5, k4 = i & 31;
    int n = n0 + r;
    float4 v = make_float4(0.f, 0.f, 0.f, 0.f);
    if (n < N_NODES) v = hp4[(size_t)n * 32 + k4];
    Hs[r * 33 + k4] = v;
  }
  __syncthreads();
  int cg = tid % 10;
  int r0 = (tid / 10) * 2;
  float4 acc0 = make_float4(0.f, 0.f, 0.f, 0.f);
  float4 acc1 = make_float4(0.f, 0.f, 0.f, 0.f);
  const float4* Wt4 = (const float4*)Wt2;
  #pragma unroll 4
  for (int k4 = 0; k4 < 32; ++k4) {
    float4 w0 = Wt4[(k4 * 4 + 0) * 10 + cg];
    float4 w1 = Wt4[(k4 * 4 + 1) * 10 + cg];
    float4 w2 = Wt4[(k4 * 4 + 2) * 10 + cg];
    float4 w3 = Wt4[(k4 * 4 + 3) * 10 + cg];
    float4 h0 = Hs[(r0    ) * 33 + k4];
    float4 h1v = Hs[(r0 + 1) * 33 + k4];
    FMA4(acc0, h0, w0, w1, w2, w3);
    FMA4(acc1, h1v, w0, w1, w2, w3);
  }
  int n = n0 + r0;
  uint2* o2p = (uint2*)Zbf;
  if (n < N_NODES) {
    uint2 p; p.x = bfpk(acc0.x, acc0.y); p.y = bfpk(acc0.z, acc0.w);
    o2p[(size_t)n * 10 + cg] = p;
  }
  if (n + 1 < N_NODES) {
    uint2 p; p.x = bfpk(acc1.x, acc1.y); p.y = bfpk(acc1.z, acc1.w);
    o2p[(size_t)(n + 1) * 10 + cg] = p;
  }
}

// ---------------------------------------------------------------------------
extern "C" void kernel_launch(void* const* d_in, const int* in_sizes, int n_in,
                              void* d_out, int out_size, void* d_ws, size_t ws_size,
                              hipStream_t stream) {
  const float* x  = (const float*)d_in[0];
  const void*  ei = d_in[1];
  const float* W1 = (const float*)d_in[2];
  const float* W2 = (const float*)d_in[3];
  float* out = (float*)d_out;

  // ws layout (4-byte units)
  int* gtot   = (int*)d_ws;                         // 1024 (zeroed in prep)
  int* gbase  = gtot + 1024;                        // 1024 (783 used)
  int* gcur   = gbase + 1024;                       // 1024
  int* rowptr = gcur + 1024;                        // 50176 (50001 used)
  int* flag   = rowptr + 50176;                     // 16
  unsigned* binned = (unsigned*)(flag + 16);        // 800000
  unsigned short* col = (unsigned short*)(binned + N_EDGES);  // 800000 ushort
  unsigned short* Ybf = col + N_EDGES;              // 6.4M bf16 (12.8MB)
  float* h1   = (float*)(Ybf + (size_t)N_NODES * 128);  // 6.4M floats
  float* Wt1  = h1 + (size_t)N_NODES * 128;         // 16384
  float* Wt2  = Wt1 + 128 * 128;                    // 5120
  unsigned short* Zbf = Ybf;                        // Z reuses dead Y region

  prep_kernel<<<86, 256, 0, stream>>>(ei, W1, W2, flag, gtot, Wt1, Wt2);
  binCount_kernel<<<NBIN_BLOCKS, 256, 0, stream>>>(ei, flag, gtot);
  bucketScan_kernel<<<1, 1024, 0, stream>>>(gtot, gbase, gcur, rowptr);
  binPlace_kernel<<<NBIN_BLOCKS, 256, 0, stream>>>(ei, flag, gcur, binned);
  csrBuild_kernel<<<NBKT, 256, 0, stream>>>(binned, gbase, rowptr, col);

  // Layer 1 (commuted): Y = x @ W1^T (bf16) ; h1 = relu(Y + A*Y) (f32)
  gemm1_kernel<<<(N_NODES + 63) / 64, 256, 0, stream>>>(x, Wt1, Ybf);
  gather1_kernel<<<(N_NODES * 64) / 256, 256, 0, stream>>>(Ybf, rowptr, col, h1);

  // Layer 2 (commuted): Z = h1 @ W2^T (bf16) ; out = Z + A*Z (f32)
  gemm2_kernel<<<(N_NODES + 63) / 64, 320, 0, stream>>>(h1, Wt2, Zbf);
  gather2_kernel<<<(N_NODES * 64) / 256, 256, 0, stream>>>(Zbf, rowptr, col, out);
}

// Round 6
// 146.104 us; speedup vs baseline: 2.8176x; 1.2126x over previous
//
#include <hip/hip_runtime.h>

#define N_NODES 50000
#define N_EDGES 800000
#define BSHIFT 6                                   // 64 nodes per bucket
#define NBKT   ((N_NODES + 63) >> BSHIFT)          // 782
#define CHUNK_EDGES 8192
#define NBIN_BLOCKS ((N_EDGES + CHUNK_EDGES - 1) / CHUNK_EDGES)  // 98

typedef __attribute__((ext_vector_type(8))) short short8;   // 8 bf16 (4 VGPRs)
typedef __attribute__((ext_vector_type(4))) float f32x4;    // MFMA acc

__device__ __forceinline__ int load_idx(const void* ei, int is64, long long pos) {
  return is64 ? (int)((const long long*)ei)[pos] : ((const int*)ei)[pos];
}

// bf16 (RNE) pack/unpack helpers
__device__ __forceinline__ unsigned bfr(float f) {
  unsigned u = __float_as_uint(f);
  return (u + 0x7FFFu + ((u >> 16) & 1u)) >> 16;
}
__device__ __forceinline__ unsigned bfpk(float lo, float hi) {
  return bfr(lo) | (bfr(hi) << 16);
}
#define ACC_BF4(acc, u)                                                    \
  acc.x += __uint_as_float((u).x << 16);                                   \
  acc.y += __uint_as_float((u).x & 0xffff0000u);                           \
  acc.z += __uint_as_float((u).y << 16);                                   \
  acc.w += __uint_as_float((u).y & 0xffff0000u);

// ---------------------------------------------------------------------------
// prep: block 0 detect; block 1 zero gtot; blocks 2..89 cast W1/W2 to bf16
// (native [o][k] layout — MFMA B-fragment wants contiguous k). W2 padded to 48 rows.
// ---------------------------------------------------------------------------
__global__ __launch_bounds__(256) void prep_kernel(const void* __restrict__ ei,
                                                   const float* __restrict__ W1,
                                                   const float* __restrict__ W2,
                                                   int* __restrict__ flag,
                                                   int* __restrict__ gtot,
                                                   unsigned short* __restrict__ W1bf,
                                                   unsigned short* __restrict__ W2bf) {
  int b = blockIdx.x, tid = threadIdx.x;
  if (b == 0) {
    if (tid < 64) {
      const long long* e64 = (const long long*)ei;
      long long v = e64[tid];
      int ok = (v >= 0 && v < N_NODES);
      unsigned long long m = __ballot(ok);
      if (tid == 0) *flag = (m == ~0ull) ? 1 : 0;
    }
  } else if (b == 1) {
    ((int4*)gtot)[tid] = make_int4(0, 0, 0, 0);   // 1024 ints
  } else {
    int j = (b - 2) * 256 + tid;                  // [0, 22528)
    if (j < 128 * 128) {
      W1bf[j] = (unsigned short)bfr(W1[j]);
    } else {
      int jj = j - 128 * 128;                     // [0, 6144)
      int c = jj >> 7, k = jj & 127;
      W2bf[jj] = (c < 40) ? (unsigned short)bfr(W2[c * 128 + k]) : 0;
    }
  }
}

// ---------------------------------------------------------------------------
// binCount: LDS-aggregated bucket histogram. 98 blocks x 8192 edges.
// ---------------------------------------------------------------------------
__global__ __launch_bounds__(256) void binCount_kernel(const void* __restrict__ ei,
                                                       const int* __restrict__ flag,
                                                       int* __restrict__ gtot) {
  __shared__ int cnt[NBKT];
  int tid = threadIdx.x;
  for (int i = tid; i < NBKT; i += 256) cnt[i] = 0;
  __syncthreads();
  int f = *flag;
  long long base = (long long)blockIdx.x * CHUNK_EDGES;
  #pragma unroll
  for (int it = 0; it < CHUNK_EDGES / 256; ++it) {
    long long e = base + it * 256 + tid;
    if (e < N_EDGES) {
      int dst = load_idx(ei, f, (long long)N_EDGES + e);
      atomicAdd(&cnt[dst >> BSHIFT], 1);
    }
  }
  __syncthreads();
  for (int i = tid; i < NBKT; i += 256) {
    int c = cnt[i];
    if (c) atomicAdd(&gtot[i], c);
  }
}

// ---------------------------------------------------------------------------
// bucketScan: exclusive scan of 782 bucket totals -> gbase/gcur.
// ---------------------------------------------------------------------------
__global__ __launch_bounds__(1024) void bucketScan_kernel(const int* __restrict__ gtot,
                                                          int* __restrict__ gbase,
                                                          int* __restrict__ gcur,
                                                          int* __restrict__ rowptr) {
  __shared__ int s[1024];
  int tid = threadIdx.x;
  s[tid] = (tid < NBKT) ? gtot[tid] : 0;
  __syncthreads();
  for (int off = 1; off < 1024; off <<= 1) {
    int t = (tid >= off) ? s[tid - off] : 0;
    __syncthreads();
    s[tid] += t;
    __syncthreads();
  }
  int excl = (tid == 0) ? 0 : s[tid - 1];
  if (tid < NBKT) { gbase[tid] = excl; gcur[tid] = excl; }
  if (tid == NBKT) gbase[NBKT] = s[NBKT - 1];   // == N_EDGES
  if (tid == 0) rowptr[N_NODES] = N_EDGES;
}

// ---------------------------------------------------------------------------
// binPlace: per-block LDS histogram -> one global reservation per bucket ->
// LDS cursors place packed edges. pk = src | dstlow<<16 | bucket<<22.
// ---------------------------------------------------------------------------
__global__ __launch_bounds__(256) void binPlace_kernel(const void* __restrict__ ei,
                                                       const int* __restrict__ flag,
                                                       int* __restrict__ gcur,
                                                       unsigned* __restrict__ binned) {
  __shared__ int cnt[NBKT];
  __shared__ int lcur[NBKT];
  int tid = threadIdx.x;
  for (int i = tid; i < NBKT; i += 256) cnt[i] = 0;
  __syncthreads();
  int f = *flag;
  long long base = (long long)blockIdx.x * CHUNK_EDGES;
  unsigned pk[CHUNK_EDGES / 256];
  #pragma unroll
  for (int it = 0; it < CHUNK_EDGES / 256; ++it) {
    long long e = base + it * 256 + tid;
    unsigned p = 0xFFFFFFFFu;
    if (e < N_EDGES) {
      int src = load_idx(ei, f, e);
      int dst = load_idx(ei, f, (long long)N_EDGES + e);
      int bk = dst >> BSHIFT;
      p = (unsigned)src | ((unsigned)(dst & 63) << 16) | ((unsigned)bk << 22);
      atomicAdd(&cnt[bk], 1);
    }
    pk[it] = p;
  }
  __syncthreads();
  for (int i = tid; i < NBKT; i += 256) {
    int c = cnt[i];
    lcur[i] = c ? atomicAdd(&gcur[i], c) : 0;
  }
  __syncthreads();
  #pragma unroll
  for (int it = 0; it < CHUNK_EDGES / 256; ++it) {
    unsigned p = pk[it];
    if (p != 0xFFFFFFFFu) {
      int bk = p >> 22;
      int slot = atomicAdd(&lcur[bk], 1);
      binned[slot] = p & 0x3FFFFFu;     // src | dstlow<<16
    }
  }
}

// ---------------------------------------------------------------------------
// csrBuild: one block per bucket (64 nodes). LDS node histogram + serial scan
// -> rowptr; then place col (ushort src) within the bucket's 2KB window.
// ---------------------------------------------------------------------------
__global__ __launch_bounds__(256) void csrBuild_kernel(const unsigned* __restrict__ binned,
                                                       const int* __restrict__ gbase,
                                                       int* __restrict__ rowptr,
                                                       unsigned short* __restrict__ col) {
  __shared__ int ncnt[64];
  __shared__ int ncur[64];
  int b = blockIdx.x, tid = threadIdx.x;
  int lo = gbase[b], hi = gbase[b + 1];
  if (tid < 64) ncnt[tid] = 0;
  __syncthreads();
  for (int i = lo + tid; i < hi; i += 256)
    atomicAdd(&ncnt[(binned[i] >> 16) & 63], 1);
  __syncthreads();
  if (tid == 0) {
    int acc = lo;
    #pragma unroll
    for (int j = 0; j < 64; ++j) { int c = ncnt[j]; ncur[j] = acc; acc += c; }
  }
  __syncthreads();
  int node0 = b << BSHIFT;
  if (tid < 64 && node0 + tid < N_NODES) rowptr[node0 + tid] = ncur[tid];
  __syncthreads();
  for (int i = lo + tid; i < hi; i += 256) {
    unsigned p = binned[i];
    int slot = atomicAdd(&ncur[(p >> 16) & 63], 1);
    col[slot] = (unsigned short)(p & 0xFFFFu);
  }
}

// ---------------------------------------------------------------------------
// gather1: h1[n] = relu(Y[n] + sum_src Y[src]); Y bf16 in, h1 bf16 out.
// ---------------------------------------------------------------------------
__global__ __launch_bounds__(256) void gather1_kernel(const unsigned short* __restrict__ Ybf,
                                                      const int* __restrict__ rowptr,
                                                      const unsigned short* __restrict__ col,
                                                      unsigned short* __restrict__ h1bf) {
  int w = (blockIdx.x * 256 + threadIdx.x) >> 6;
  if (w >= N_NODES) return;
  int lane = threadIdx.x & 63;
  int h = lane >> 5;
  int q = lane & 31;
  const uint2* Y2 = (const uint2*)Ybf;
  float4 acc = make_float4(0.f, 0.f, 0.f, 0.f);
  if (h == 0) {
    uint2 u = Y2[(size_t)w * 32 + q];
    ACC_BF4(acc, u);
  }
  int i = rowptr[w] + h, end = rowptr[w + 1];
  for (; i + 6 < end; i += 8) {
    int s0 = col[i], s1 = col[i + 2], s2 = col[i + 4], s3 = col[i + 6];
    uint2 u0 = Y2[(size_t)s0 * 32 + q];
    uint2 u1 = Y2[(size_t)s1 * 32 + q];
    uint2 u2 = Y2[(size_t)s2 * 32 + q];
    uint2 u3 = Y2[(size_t)s3 * 32 + q];
    ACC_BF4(acc, u0); ACC_BF4(acc, u1); ACC_BF4(acc, u2); ACC_BF4(acc, u3);
  }
  for (; i < end; i += 2) {
    uint2 u0 = Y2[(size_t)col[i] * 32 + q];
    ACC_BF4(acc, u0);
  }
  acc.x += __shfl_xor(acc.x, 32);
  acc.y += __shfl_xor(acc.y, 32);
  acc.z += __shfl_xor(acc.z, 32);
  acc.w += __shfl_xor(acc.w, 32);
  if (h == 0) {
    uint2 p;
    p.x = bfpk(fmaxf(acc.x, 0.f), fmaxf(acc.y, 0.f));
    p.y = bfpk(fmaxf(acc.z, 0.f), fmaxf(acc.w, 0.f));
    ((uint2*)h1bf)[(size_t)w * 32 + q] = p;
  }
}

// ---------------------------------------------------------------------------
// gather2: out[n] = Z[n] + sum_src Z[src]; Z bf16, 40/row (10 uint2); out f32.
// ---------------------------------------------------------------------------
__global__ __launch_bounds__(256) void gather2_kernel(const unsigned short* __restrict__ Zbf,
                                                      const int* __restrict__ rowptr,
                                                      const unsigned short* __restrict__ col,
                                                      float* __restrict__ outp) {
  int w = (blockIdx.x * 256 + threadIdx.x) >> 6;
  if (w >= N_NODES) return;
  int lane = threadIdx.x & 63;
  int h = lane >> 4;
  int q = lane & 15;
  bool act = q < 10;
  const uint2* Z2 = (const uint2*)Zbf;
  float4 acc = make_float4(0.f, 0.f, 0.f, 0.f);
  if (h == 0 && act) {
    uint2 u = Z2[(size_t)w * 10 + q];
    ACC_BF4(acc, u);
  }
  int i = rowptr[w] + h, end = rowptr[w + 1];
  for (; i + 4 < end; i += 8) {
    int s0 = col[i], s1 = col[i + 4];
    if (act) {
      uint2 u0 = Z2[(size_t)s0 * 10 + q];
      uint2 u1 = Z2[(size_t)s1 * 10 + q];
      ACC_BF4(acc, u0); ACC_BF4(acc, u1);
    }
  }
  for (; i < end; i += 4) {
    int s0 = col[i];
    if (act) {
      uint2 u0 = Z2[(size_t)s0 * 10 + q];
      ACC_BF4(acc, u0);
    }
  }
  acc.x += __shfl_xor(acc.x, 16);
  acc.y += __shfl_xor(acc.y, 16);
  acc.z += __shfl_xor(acc.z, 16);
  acc.w += __shfl_xor(acc.w, 16);
  acc.x += __shfl_xor(acc.x, 32);
  acc.y += __shfl_xor(acc.y, 32);
  acc.z += __shfl_xor(acc.z, 32);
  acc.w += __shfl_xor(acc.w, 32);
  if (h == 0 && act)
    ((float4*)outp)[(size_t)w * 10 + q] = acc;
}

// ---------------------------------------------------------------------------
// MFMA GEMM1: Y[n][o] = sum_k x[n][k]*W1[o][k]. 64 rows/block, 4 waves x 16
// rows, 8 out-tiles, K=128 in 4 steps of 32. A: x cast f32->bf16 in-reg.
// B: W1bf native [o][k] (lane o=l&15, k contiguous 8). Epilogue via LDS.
// ---------------------------------------------------------------------------
__global__ __launch_bounds__(256) void gemm1_kernel(const float* __restrict__ xin,
                                                    const unsigned short* __restrict__ W1bf,
                                                    unsigned short* __restrict__ Ybf) {
  __shared__ unsigned short Ysh[64 * 128];
  int tid = threadIdx.x;
  int wave = tid >> 6, lane = tid & 63;
  int rl = lane & 15, kg = lane >> 4;      // kg = 0..3
  int n0 = blockIdx.x * 64;
  int rowg = n0 + wave * 16 + rl;
  int row = (rowg < N_NODES) ? rowg : (N_NODES - 1);
  f32x4 acc[8];
  #pragma unroll
  for (int t = 0; t < 8; ++t) acc[t] = (f32x4)(0.f);
  #pragma unroll
  for (int kk = 0; kk < 4; ++kk) {
    int k0 = kk * 32 + kg * 8;
    const float* xr = xin + (size_t)row * 128 + k0;
    float4 a0 = *(const float4*)xr;
    float4 a1 = *(const float4*)(xr + 4);
    short8 a;
    a[0] = (short)bfr(a0.x); a[1] = (short)bfr(a0.y);
    a[2] = (short)bfr(a0.z); a[3] = (short)bfr(a0.w);
    a[4] = (short)bfr(a1.x); a[5] = (short)bfr(a1.y);
    a[6] = (short)bfr(a1.z); a[7] = (short)bfr(a1.w);
    #pragma unroll
    for (int t = 0; t < 8; ++t) {
      short8 b = *(const short8*)(W1bf + (t * 16 + rl) * 128 + k0);
      acc[t] = __builtin_amdgcn_mfma_f32_16x16x32_bf16(a, b, acc[t], 0, 0, 0);
    }
  }
  // C/D: col = lane&15 (=rl), row = kg*4 + reg  (within wave's 16 rows)
  #pragma unroll
  for (int t = 0; t < 8; ++t) {
    #pragma unroll
    for (int reg = 0; reg < 4; ++reg)
      Ysh[(wave * 16 + kg * 4 + reg) * 128 + t * 16 + rl] =
          (unsigned short)bfr(acc[t][reg]);
  }
  __syncthreads();
  int rows = N_NODES - n0; if (rows > 64) rows = 64;
  uint4* dst = (uint4*)(Ybf + (size_t)n0 * 128);
  const uint4* src = (const uint4*)Ysh;
  for (int i = tid; i < rows * 16; i += 256) dst[i] = src[i];
}

// ---------------------------------------------------------------------------
// MFMA GEMM2: Z[n][c] = sum_k h1[n][k]*W2[c][k], c<40 (3 out-tiles, padded 48).
// A read directly from h1 bf16. Epilogue via LDS (row stride 40).
// ---------------------------------------------------------------------------
__global__ __launch_bounds__(256) void gemm2_kernel(const unsigned short* __restrict__ h1bf,
                                                    const unsigned short* __restrict__ W2bf,
                                                    unsigned short* __restrict__ Zbf) {
  __shared__ unsigned short Zsh[64 * 40];
  int tid = threadIdx.x;
  int wave = tid >> 6, lane = tid & 63;
  int rl = lane & 15, kg = lane >> 4;
  int n0 = blockIdx.x * 64;
  int rowg = n0 + wave * 16 + rl;
  int row = (rowg < N_NODES) ? rowg : (N_NODES - 1);
  f32x4 acc[3];
  #pragma unroll
  for (int t = 0; t < 3; ++t) acc[t] = (f32x4)(0.f);
  #pragma unroll
  for (int kk = 0; kk < 4; ++kk) {
    int k0 = kk * 32 + kg * 8;
    short8 a = *(const short8*)(h1bf + (size_t)row * 128 + k0);
    #pragma unroll
    for (int t = 0; t < 3; ++t) {
      short8 b = *(const short8*)(W2bf + (t * 16 + rl) * 128 + k0);
      acc[t] = __builtin_amdgcn_mfma_f32_16x16x32_bf16(a, b, acc[t], 0, 0, 0);
    }
  }
  #pragma unroll
  for (int t = 0; t < 3; ++t) {
    int c = t * 16 + rl;
    if (c < 40) {
      #pragma unroll
      for (int reg = 0; reg < 4; ++reg)
        Zsh[(wave * 16 + kg * 4 + reg) * 40 + c] = (unsigned short)bfr(acc[t][reg]);
    }
  }
  __syncthreads();
  int rows = N_NODES - n0; if (rows > 64) rows = 64;
  unsigned* dst = (unsigned*)Zbf + (size_t)n0 * 20;
  const unsigned* src = (const unsigned*)Zsh;
  for (int i = tid; i < rows * 20; i += 256) dst[i] = src[i];
}

// ---------------------------------------------------------------------------
extern "C" void kernel_launch(void* const* d_in, const int* in_sizes, int n_in,
                              void* d_out, int out_size, void* d_ws, size_t ws_size,
                              hipStream_t stream) {
  const float* x  = (const float*)d_in[0];
  const void*  ei = d_in[1];
  const float* W1 = (const float*)d_in[2];
  const float* W2 = (const float*)d_in[3];
  float* out = (float*)d_out;

  // ws layout (4-byte units; all bf16 buffers 16B-aligned)
  int* gtot   = (int*)d_ws;                         // 1024 (zeroed in prep)
  int* gbase  = gtot + 1024;                        // 1024 (783 used)
  int* gcur   = gbase + 1024;                       // 1024
  int* rowptr = gcur + 1024;                        // 50176 (50001 used)
  int* flag   = rowptr + 50176;                     // 16
  unsigned* binned = (unsigned*)(flag + 16);        // 800000
  unsigned short* col  = (unsigned short*)(binned + N_EDGES);    // 800000 ushort
  unsigned short* Ybf  = col + N_EDGES;             // 6.4M bf16 (12.8MB)
  unsigned short* h1bf = Ybf + (size_t)N_NODES * 128;  // 6.4M bf16
  unsigned short* W1bf = h1bf + (size_t)N_NODES * 128; // 16384 bf16
  unsigned short* W2bf = W1bf + 128 * 128;          // 48*128 bf16 (padded)
  unsigned short* Zbf  = Ybf;                       // Z reuses dead Y region

  prep_kernel<<<90, 256, 0, stream>>>(ei, W1, W2, flag, gtot, W1bf, W2bf);
  binCount_kernel<<<NBIN_BLOCKS, 256, 0, stream>>>(ei, flag, gtot);
  bucketScan_kernel<<<1, 1024, 0, stream>>>(gtot, gbase, gcur, rowptr);
  binPlace_kernel<<<NBIN_BLOCKS, 256, 0, stream>>>(ei, flag, gcur, binned);
  csrBuild_kernel<<<NBKT, 256, 0, stream>>>(binned, gbase, rowptr, col);

  // Layer 1 (commuted): Y = x @ W1^T (MFMA, bf16) ; h1 = relu(Y + A*Y) (bf16)
  gemm1_kernel<<<(N_NODES + 63) / 64, 256, 0, stream>>>(x, W1bf, Ybf);
  gather1_kernel<<<(N_NODES * 64) / 256, 256, 0, stream>>>(Ybf, rowptr, col, h1bf);

  // Layer 2 (commuted): Z = h1 @ W2^T (MFMA, bf16) ; out = Z + A*Z (f32)
  gemm2_kernel<<<(N_NODES + 63) / 64, 256, 0, stream>>>(h1bf, W2bf, Zbf);
  gather2_kernel<<<(N_NODES * 64) / 256, 256, 0, stream>>>(Zbf, rowptr, col, out);
}